// Round 3
// baseline (527.019 us; speedup 1.0000x reference)
//
#include <hip/hip_runtime.h>
#include <stdint.h>

// ---------- types ----------
typedef __attribute__((ext_vector_type(8))) short bf16x8;   // 8 bf16 in 4 VGPRs
typedef __attribute__((ext_vector_type(4))) float f32x4;

__device__ __forceinline__ float bf2f(short u){
  union { float f; uint32_t i; } v; v.i = ((uint32_t)(uint16_t)u) << 16; return v.f;
}
__device__ __forceinline__ short f2bf(float x){
  union { float f; uint32_t i; } v; v.f = x;
  uint32_t r = v.i + 0x7FFFu + ((v.i >> 16) & 1u);   // RNE
  return (short)(r >> 16);
}

// async global->LDS, 16B per lane; LDS dest = wave-uniform base + lane*16
__device__ __forceinline__ void gl_lds16(const short* g, short* l){
  __builtin_amdgcn_global_load_lds(
      (__attribute__((address_space(1))) void*)(short*)g,
      (__attribute__((address_space(3))) void*)l, 16, 0, 0);
}

// ---------- permutation tables (WIN=7, compile-time) ----------
__device__ const int d_DIAG[49] = {0,1,7,2,8,14,3,9,15,21,4,10,16,22,28,5,11,17,23,29,35,
  6,12,18,24,30,36,42,13,19,25,31,37,43,20,26,32,38,44,27,33,39,45,34,40,46,41,47,48};
__device__ const int d_ANTI[49] = {6,5,13,4,12,20,3,11,19,27,2,10,18,26,34,1,9,17,25,33,41,
  0,8,16,24,32,40,48,7,15,23,31,39,47,14,22,30,38,46,21,29,37,45,28,36,44,35,43,42};

__device__ __forceinline__ int perm_idx(int g, int l){
  if (g == 0) return l;
  if (g == 1) return (l % 7) * 7 + l / 7;  // V_IDX
  if (g == 2) return d_DIAG[l];
  return d_ANTI[l];
}

// ---------- shared K-loop: triple-buffered, 2-deep prefetch, counted vmcnt ----------
// LDS layout per matrix: [128 rows][4 slots of 8 shorts] per buffer (8KB), 3 buffers.
// Slot XOR-swizzle: LDS slot s of row r holds global chunk s ^ ((r>>1)&3).
// Write side is linear (global_load_lds requirement); the permutation is applied
// to the per-lane GLOBAL source chunk; reads apply the same XOR. Any 8
// consecutive lanes of ds_read_b128 then cover all 8 16B-slots of a 128B bank
// window -> conflict-free.
template<int NT>
__device__ __forceinline__ void kloop_pf(
    const short* a0, const short* a1, const short* b0, const short* b1,
    int lds0, int lds1, short* As, short* Bs,
    int quad, int mr, int wm, int wn, f32x4 acc[4][4])
{
  auto STAGE = [&](int t){
    int b = t % 3;
    gl_lds16(a0 + t*32, As + b*4096 + lds0);
    gl_lds16(a1 + t*32, As + b*4096 + lds1);
    gl_lds16(b0 + t*32, Bs + b*4096 + lds0);
    gl_lds16(b1 + t*32, Bs + b*4096 + lds1);
  };
  int sw = (quad ^ ((mr >> 1) & 3)) * 8;     // swizzled slot offset (shorts)
  STAGE(0); STAGE(1);
  for (int t = 0; t < NT; ++t){
    if (t + 2 < NT){
      STAGE(t + 2);
      asm volatile("s_waitcnt vmcnt(8)" ::: "memory");   // tile t's 4 loads done
    } else if (t + 1 < NT){
      asm volatile("s_waitcnt vmcnt(4)" ::: "memory");
    } else {
      asm volatile("s_waitcnt vmcnt(0)" ::: "memory");
    }
    __builtin_amdgcn_s_barrier();            // all waves: tile t resident in LDS
    __builtin_amdgcn_sched_barrier(0);
    const short* Ab = As + (t % 3) * 4096;
    const short* Bb = Bs + (t % 3) * 4096;
    bf16x8 af[4], bfr[4];
    #pragma unroll
    for (int x = 0; x < 4; x++){
      af[x]  = *(const bf16x8*)(Ab + (wm + x*16 + mr)*32 + sw);
      bfr[x] = *(const bf16x8*)(Bb + (wn + x*16 + mr)*32 + sw);
    }
    #pragma unroll
    for (int mt = 0; mt < 4; mt++)
      #pragma unroll
      for (int nt2 = 0; nt2 < 4; nt2++)
        acc[mt][nt2] = __builtin_amdgcn_mfma_f32_16x16x32_bf16(af[mt], bfr[nt2], acc[mt][nt2],0,0,0);
    __builtin_amdgcn_sched_barrier(0);
    __builtin_amdgcn_s_barrier();            // all waves done reading buf (t%3)
  }
}

// ---------- prep: plain f32->bf16 converts (in_proj, post x4, x_proj_w, dt_proj_w) ----------
__global__ __launch_bounds__(256) void k_conv_all(
    const float* __restrict__ in_proj,
    const float* __restrict__ pw0, const float* __restrict__ pw1,
    const float* __restrict__ pw2, const float* __restrict__ pw3,
    const float* __restrict__ xpw, const float* __restrict__ dtw,
    short* __restrict__ inp_bf, short* __restrict__ postw_bf,
    short* __restrict__ xpw_bf, short* __restrict__ dtw_bf)
{
  int q = blockIdx.x*256 + threadIdx.x;   // quad index, total 332800
  const float* src; short* dst; int off;
  if (q < 65536){ src = in_proj; dst = inp_bf; off = q; }
  else if (q < 65536 + 262144){
    int r = q - 65536; int g = r >> 16; int loc = r & 65535;
    src = (g==0)?pw0:(g==1)?pw1:(g==2)?pw2:pw3;
    dst = postw_bf + g*262144; off = loc;
  }
  else if (q < 65536 + 262144 + 3072){ src = xpw; dst = xpw_bf; off = q - (65536+262144); }
  else { src = dtw; dst = dtw_bf; off = q - (65536+262144+3072); }
  float4 v = *(const float4*)(src + off*4);
  uint32_t p0 = (uint32_t)(uint16_t)f2bf(v.x) | ((uint32_t)(uint16_t)f2bf(v.y) << 16);
  uint32_t p1 = (uint32_t)(uint16_t)f2bf(v.z) | ((uint32_t)(uint16_t)f2bf(v.w) << 16);
  uint2 p; p.x = p0; p.y = p1;
  *(uint2*)(dst + off*4) = p;
}

// ---------- prep: LDS-tiled transpose+convert (pre_w x4 -> wpreT, out_proj -> woutT) ----------
__global__ __launch_bounds__(256) void k_transp(
    const float* __restrict__ pw0, const float* __restrict__ pw1,
    const float* __restrict__ pw2, const float* __restrict__ pw3,
    const float* __restrict__ outp,
    short* __restrict__ wpreT, short* __restrict__ woutT)
{
  __shared__ float tile[64][65];
  int which = blockIdx.y;
  const float* src = (which==0)?pw0:(which==1)?pw1:(which==2)?pw2:(which==3)?pw3:outp;
  short* dst = (which < 4) ? (wpreT + which*262144) : woutT;
  int bi = blockIdx.x >> 3, bj = blockIdx.x & 7;
  int r0 = bi*64, c0 = bj*64;
  int t = threadIdx.x;
  int row = t >> 2, cg = t & 3;
  const float4* s4 = (const float4*)(src + (r0+row)*512 + c0 + cg*16);
  #pragma unroll
  for (int i=0;i<4;i++){
    float4 v = s4[i];
    tile[row][cg*16 + i*4 + 0] = v.x;
    tile[row][cg*16 + i*4 + 1] = v.y;
    tile[row][cg*16 + i*4 + 2] = v.z;
    tile[row][cg*16 + i*4 + 3] = v.w;
  }
  __syncthreads();
  int oc = t >> 2;
  short tmp[16];
  #pragma unroll
  for (int i=0;i<16;i++) tmp[i] = f2bf(tile[cg*16 + i][oc]);
  short* dp = dst + (size_t)(c0+oc)*512 + r0 + cg*16;
  *(bf16x8*)(dp)     = *(bf16x8*)tmp;
  *(bf16x8*)(dp + 8) = *((bf16x8*)tmp + 1);
}

__global__ __launch_bounds__(256) void k_tok(const float* __restrict__ t, short* __restrict__ o){
  int i = (blockIdx.x*256 + threadIdx.x) * 4;
  float4 v = *(const float4*)(t + i);
  uint32_t p0 = (uint32_t)(uint16_t)f2bf(v.x) | ((uint32_t)(uint16_t)f2bf(v.y) << 16);
  uint32_t p1 = (uint32_t)(uint16_t)f2bf(v.z) | ((uint32_t)(uint16_t)f2bf(v.w) << 16);
  uint2 p; p.x = p0; p.y = p1;
  *(uint2*)(o + i) = p;
}

// ---------- prep: b_xz (blocks 0-7) + gains/biasc (block 8) ----------
__global__ __launch_bounds__(256) void k_bxz_gains(const float* __restrict__ in_proj,
    const float* __restrict__ b0, const float* __restrict__ b1,
    const float* __restrict__ b2, const float* __restrict__ b3,
    const float* __restrict__ gl,
    const float* __restrict__ pb0, const float* __restrict__ pb1,
    const float* __restrict__ pb2, const float* __restrict__ pb3,
    float* __restrict__ bxz, float* __restrict__ gains, float* __restrict__ biasc)
{
  if (blockIdx.x < 8){
    int idx = blockIdx.x*256 + threadIdx.x;   // 0..2047
    int g = idx >> 9, i = idx & 511;
    const float* bb = (g==0)?b0:(g==1)?b1:(g==2)?b2:b3;
    float s = 0.f;
    for (int t=0;t<512;t++) s += in_proj[i*512+t]*bb[t];
    bxz[idx] = s;
  } else {
    float m = fmaxf(fmaxf(gl[0], gl[1]), fmaxf(gl[2], gl[3]));
    float e0 = expf(gl[0]-m), e1 = expf(gl[1]-m), e2 = expf(gl[2]-m), e3 = expf(gl[3]-m);
    float s = e0+e1+e2+e3;
    float g0 = e0/s, g1 = e1/s, g2 = e2/s, g3 = e3/s;
    int t = threadIdx.x;
    if (t == 0){ gains[0]=g0; gains[1]=g1; gains[2]=g2; gains[3]=g3; }
    biasc[t]     = g0*pb0[t]     + g1*pb1[t]     + g2*pb2[t]     + g3*pb3[t];
    biasc[t+256] = g0*pb0[t+256] + g1*pb1[t+256] + g2*pb2[t+256] + g3*pb3[t+256];
  }
}

// ---------- register-GEMM core for the tiny weight-fuse GEMMs ----------
__device__ __forceinline__ void mfma_2x4_k(const short* a0, const short* a1,
    const short* b0, const short* b1, const short* b2, const short* b3,
    int K, f32x4 acc[2][4])
{
  for (int k0 = 0; k0 < K; k0 += 32){
    bf16x8 av0 = *(const bf16x8*)(a0 + k0);
    bf16x8 av1 = *(const bf16x8*)(a1 + k0);
    bf16x8 bv0 = *(const bf16x8*)(b0 + k0);
    bf16x8 bv1 = *(const bf16x8*)(b1 + k0);
    bf16x8 bv2 = *(const bf16x8*)(b2 + k0);
    bf16x8 bv3 = *(const bf16x8*)(b3 + k0);
    acc[0][0] = __builtin_amdgcn_mfma_f32_16x16x32_bf16(av0, bv0, acc[0][0],0,0,0);
    acc[0][1] = __builtin_amdgcn_mfma_f32_16x16x32_bf16(av0, bv1, acc[0][1],0,0,0);
    acc[0][2] = __builtin_amdgcn_mfma_f32_16x16x32_bf16(av0, bv2, acc[0][2],0,0,0);
    acc[0][3] = __builtin_amdgcn_mfma_f32_16x16x32_bf16(av0, bv3, acc[0][3],0,0,0);
    acc[1][0] = __builtin_amdgcn_mfma_f32_16x16x32_bf16(av1, bv0, acc[1][0],0,0,0);
    acc[1][1] = __builtin_amdgcn_mfma_f32_16x16x32_bf16(av1, bv1, acc[1][1],0,0,0);
    acc[1][2] = __builtin_amdgcn_mfma_f32_16x16x32_bf16(av1, bv2, acc[1][2],0,0,0);
    acc[1][3] = __builtin_amdgcn_mfma_f32_16x16x32_bf16(av1, bv3, acc[1][3],0,0,0);
  }
}

// ---------- merged weight-fuse: z<4 -> W_xz[g]; z>=4 -> Wog[g] ----------
__global__ __launch_bounds__(256) void k_wfuse(const short* __restrict__ inp_bf,
    const short* __restrict__ wpreT, const short* __restrict__ postw_bf,
    const short* __restrict__ woutT, const float* __restrict__ gains,
    short* __restrict__ wxz, short* __restrict__ wogc)
{
  int z = blockIdx.z; int g = z & 3, which = z >> 2;
  int bn = blockIdx.x * 64, bm = blockIdx.y * 128;
  int lane = threadIdx.x & 63, wave = threadIdx.x >> 6;
  int mr = lane & 15, qk = (lane >> 4) * 8, quad = lane >> 4;
  const short* Am = which ? (postw_bf + g*262144) : inp_bf;
  const short* Bm = which ? woutT : (wpreT + g*262144);
  const short* a0 = Am + (bm + wave*32 + mr)*512 + qk;
  const short* a1 = a0 + 16*512;
  const short* b0 = Bm + (bn +  0 + mr)*512 + qk;
  const short* b1 = Bm + (bn + 16 + mr)*512 + qk;
  const short* b2 = Bm + (bn + 32 + mr)*512 + qk;
  const short* b3 = Bm + (bn + 48 + mr)*512 + qk;
  f32x4 acc[2][4] = {};
  mfma_2x4_k(a0, a1, b0, b1, b2, b3, 512, acc);
  float gain = which ? gains[g] : 1.f;
  #pragma unroll
  for (int s=0;s<2;s++)
    #pragma unroll
    for (int t=0;t<4;t++)
      #pragma unroll
      for (int r=0;r<4;r++){
        int row = bm + wave*32 + s*16 + quad*4 + r;
        int col = bn + t*16 + mr;
        if (which) wogc[row*2048 + g*512 + col] = f2bf(gain * acc[s][t][r]);
        else       wxz[g*262144 + row*512 + col] = f2bf(acc[s][t][r]);
      }
}

// ---------- GEMM1 (prefetched): 128x128 tile, BK=32, K=512, XCD-swizzled ----------
// xz[(g*512+b)*49+l][ch] = tok[b][perm_g(l)][:] @ W_xz[g]^T + b_xz[g]
__global__ __launch_bounds__(256) void k_gemm1(const short* __restrict__ tok,
    const short* __restrict__ wxz, const float* __restrict__ bxz, short* __restrict__ xz)
{
  __shared__ __align__(16) short As[12288];   // 3 buffers x 8KB, [128 rows][4 slots x 8]
  __shared__ __align__(16) short Bs[12288];
  int g = blockIdx.z;
  int bid = blockIdx.x;                       // 784 = 8 * 98, bijective XCD swizzle
  int swz = (bid & 7) * 98 + (bid >> 3);
  int bn = (swz & 3) * 128, bm = (swz >> 2) * 128;
  int tid = threadIdx.x, lane = tid & 63, wave = tid >> 6;

  const short* aG[2]; const short* bG[2]; int ldsOff[2];
  #pragma unroll
  for (int i = 0; i < 2; i++){
    int c = wave*2 + i;
    int r = c*16 + (lane >> 2);       // row within 128-tile (16 rows per instr)
    int ch = ((lane & 3) ^ ((lane >> 3) & 3)) * 8;   // pre-swizzled global chunk
    int grow = bm + r;
    int b = grow / 49, l = grow - b*49;
    int sl = perm_idx(g, l);
    aG[i] = tok + ((size_t)(b*49 + sl))*512 + ch;
    bG[i] = wxz + (size_t)g*262144 + (size_t)(bn + r)*512 + ch;
    ldsOff[i] = c*512;
  }

  int mr = lane & 15, quad = lane >> 4;
  int wm = (wave & 1)*64, wn = (wave >> 1)*64;
  f32x4 acc[4][4] = {};

  kloop_pf<16>(aG[0], aG[1], bG[0], bG[1], ldsOff[0], ldsOff[1],
               As, Bs, quad, mr, wm, wn, acc);

  #pragma unroll
  for (int mt = 0; mt < 4; mt++)
    #pragma unroll
    for (int rr = 0; rr < 4; rr++){
      int row = bm + wm + mt*16 + quad*4 + rr;
      int b = row / 49, l = row - b*49;
      size_t orow = ((size_t)(g*512 + b)*49 + l)*512;
      #pragma unroll
      for (int nt = 0; nt < 4; nt++){
        int col = bn + wn + nt*16 + mr;
        xz[orow + col] = f2bf(acc[mt][nt][rr] + bxz[g*512 + col]);
      }
    }
}

// ---------- k_conv: depthwise conv3 + SiLU, fully parallel ----------
__global__ __launch_bounds__(256) void k_conv(const short* __restrict__ xz,
    const float* __restrict__ cxw, const float* __restrict__ cxb,
    const float* __restrict__ czw, const float* __restrict__ czb,
    short* __restrict__ ycat)
{
  int t = threadIdx.x;
  int oct = t & 63, lstart = t >> 6;
  int ch0 = oct * 8;
  bool isx = ch0 < 256;
  int cc0 = isx ? ch0 : ch0 - 256;
  const float* wsrc = isx ? cxw : czw;
  const float* bsrc = isx ? cxb : czb;
  float w0[8], w1[8], w2[8], bb[8];
  #pragma unroll
  for (int e=0;e<8;e++){
    w0[e] = wsrc[(cc0+e)*3]; w1[e] = wsrc[(cc0+e)*3+1]; w2[e] = wsrc[(cc0+e)*3+2];
    bb[e] = bsrc[cc0+e];
  }
  int gb = blockIdx.x; int g = gb >> 9, b = gb & 511;
  const short* src = xz + (size_t)gb*25088 + ch0;
  short* dst = ycat + (size_t)(b*49)*2048 + g*512 + ch0;
  for (int l = lstart; l < 49; l += 4){
    bf16x8 vm = {}, vp = {};
    bf16x8 v0 = *(const bf16x8*)(src + l*512);
    if (l > 0)  vm = *(const bf16x8*)(src + (l-1)*512);
    if (l < 48) vp = *(const bf16x8*)(src + (l+1)*512);
    short ov[8];
    #pragma unroll
    for (int e=0;e<8;e++){
      float x = w0[e]*bf2f(vm[e]) + w1[e]*bf2f(v0[e]) + w2[e]*bf2f(vp[e]) + bb[e];
      ov[e] = f2bf(x / (1.f + __expf(-x)));
    }
    *(bf16x8*)(dst + l*2048) = *(bf16x8*)ov;
  }
}

// ---------- k_xproj: x_proj GEMM + LN + dt GEMM + softplus ----------
__global__ __launch_bounds__(256) void k_xproj(const short* __restrict__ ycat,
    const short* __restrict__ xpw_bf, const float* __restrict__ lnw, const float* __restrict__ lnb,
    const short* __restrict__ dtw_bf, const float* __restrict__ dtb,
    short* __restrict__ dtln, float* __restrict__ bc)
{
  // LDS: xd f32 [128][52] = 26624 B ; xln_bf bf16 [128][40] = 10240 B
  __shared__ __align__(16) char smem[36864];
  float* xd = (float*)smem;
  short* xln = (short*)(smem + 26624);

  int bm = blockIdx.x * 128;
  int g = bm / 25088;                   // uniform per block (128 | 25088)
  int tid = threadIdx.x, lane = tid & 63, w = tid >> 6;
  int mr = lane & 15, quad = lane >> 4, qk = quad * 8;

  // ---- phase 1: x_dbl = u @ xpw^T  (tile 128x48, K=256) ----
  {
    const short* ap[2];
    #pragma unroll
    for (int s=0;s<2;s++)
      ap[s] = ycat + (size_t)(bm - g*25088 + w*32 + s*16 + mr)*2048 + g*512 + qk;
    f32x4 acc[2][3] = {};
    #pragma unroll
    for (int k0 = 0; k0 < 256; k0 += 32){
      bf16x8 av[2];
      #pragma unroll
      for (int s=0;s<2;s++) av[s] = *(const bf16x8*)(ap[s] + k0);
      #pragma unroll
      for (int t=0;t<3;t++){
        bf16x8 bv = *(const bf16x8*)(xpw_bf + (t*16 + mr)*256 + qk + k0);
        #pragma unroll
        for (int s=0;s<2;s++)
          acc[s][t] = __builtin_amdgcn_mfma_f32_16x16x32_bf16(av[s], bv, acc[s][t],0,0,0);
      }
    }
    #pragma unroll
    for (int s=0;s<2;s++)
      #pragma unroll
      for (int t=0;t<3;t++)
        #pragma unroll
        for (int r=0;r<4;r++)
          xd[(w*32 + s*16 + quad*4 + r)*52 + t*16 + mr] = acc[s][t][r];
  }
  __syncthreads();

  // ---- phase 2: LN per row (threads 0..127), write dt-cols to xln (bf16) + B/C to global ----
  if (tid < 128){
    f32x4* xr4 = (f32x4*)(xd + tid*52);
    f32x4 s = xr4[0];
    #pragma unroll
    for (int i=1;i<12;i++) s += xr4[i];
    float m = (s[0]+s[1]+s[2]+s[3]) * (1.f/48.f);
    f32x4 vs = {};
    #pragma unroll
    for (int i=0;i<12;i++){ f32x4 d = xr4[i] - m; vs += d*d; }
    float var = (vs[0]+vs[1]+vs[2]+vs[3]) * (1.f/48.f);
    float rstd = rsqrtf(var + 1e-5f);
    const f32x4* g4 = (const f32x4*)lnw;
    const f32x4* b4 = (const f32x4*)lnb;
    uint32_t* xlr = (uint32_t*)(xln + tid*40);
    #pragma unroll
    for (int i=0;i<8;i++){       // cols 0..31 -> xln bf16
      f32x4 v = (xr4[i] - m) * rstd * g4[i] + b4[i];
      xlr[2*i]   = (uint32_t)(uint16_t)f2bf(v[0]) | ((uint32_t)(uint16_t)f2bf(v[1]) << 16);
      xlr[2*i+1] = (uint32_t)(uint16_t)f2bf(v[2]) | ((uint32_t)(uint16_t)f2bf(v[3]) << 16);
    }
    f32x4* bco = (f32x4*)(bc + (size_t)(bm + tid)*16);
    #pragma unroll
    for (int i=8;i<12;i++)       // cols 32..47 -> bc f32
      bco[i-8] = (xr4[i] - m) * rstd * g4[i] + b4[i];
  }
  __syncthreads();

  // ---- phase 3: dt = xln[:,0:32] @ dtw^T (K=32, N=256) + bias + softplus -> dtln ----
  // softplus via hardware exp2/log2 path; for x>15 select x (err << bf16 ulp).
  {
    bf16x8 a[2];
    #pragma unroll
    for (int s=0;s<2;s++)
      a[s] = *(const bf16x8*)(xln + (w*32 + s*16 + mr)*40 + qk);
    #pragma unroll 4
    for (int nt=0; nt<16; nt++){
      int col = nt*16 + mr;
      bf16x8 bv = *(const bf16x8*)(dtw_bf + col*32 + qk);
      float dtbv = dtb[col];
      #pragma unroll
      for (int s=0;s<2;s++){
        f32x4 acc = {};
        acc = __builtin_amdgcn_mfma_f32_16x16x32_bf16(a[s], bv, acc,0,0,0);
        #pragma unroll
        for (int r=0;r<4;r++){
          int grow = bm + w*32 + s*16 + quad*4 + r;
          float dtv = acc[r] + dtbv;
          float e  = __expf(dtv);
          float sp = __logf(1.f + e);
          float delta = (dtv > 15.f) ? dtv : sp;
          dtln[(size_t)grow*256 + col] = f2bf(delta);
        }
      }
    }
  }
}

// ---------- k_scan: selective scan, one block per gb, u->y in place ----------
__global__ __launch_bounds__(256) void k_scan(short* __restrict__ ycat,
    const short* __restrict__ dtln, const float* __restrict__ bc,
    const float* __restrict__ Alog, const float* __restrict__ Dp)
{
  __shared__ __align__(16) float bcs[784];   // [49][16]
  int gb = blockIdx.x; int g = gb >> 9, b = gb & 511;
  int d = threadIdx.x;
  if (d < 196) ((f32x4*)bcs)[d] = ((const f32x4*)(bc + (size_t)gb*784))[d];
  __syncthreads();

  float A[8], h[8];
  {
    f32x4 a0 = *(const f32x4*)(Alog + d*8);
    f32x4 a1 = *(const f32x4*)(Alog + d*8 + 4);
    #pragma unroll
    for (int n=0;n<4;n++){ A[n] = -__expf(a0[n]); A[n+4] = -__expf(a1[n]); h[n]=0.f; h[n+4]=0.f; }
  }
  float Dpar = Dp[d];

  const short* dptr = dtln + (size_t)gb*49*256 + d;
  short* uptr = ycat + (size_t)(b*49)*2048 + g*512 + d;

  float dn = bf2f(dptr[0]);
  float un = bf2f(uptr[0]);
  for (int l=0;l<49;l++){
    float delta = dn, u = un;
    if (l < 48){ dn = bf2f(dptr[(l+1)*256]); un = bf2f(uptr[(l+1)*2048]); }
    const f32x4* bcr = (const f32x4*)(bcs + l*16);
    f32x4 B0 = bcr[0], B1 = bcr[1], C0 = bcr[2], C1 = bcr[3];
    float du = delta * u;
    float y = 0.f;
    #pragma unroll
    for (int n=0;n<4;n++){
      h[n] = h[n]*__expf(delta*A[n]) + du*B0[n];
      y += h[n]*C0[n];
    }
    #pragma unroll
    for (int n=0;n<4;n++){
      h[n+4] = h[n+4]*__expf(delta*A[n+4]) + du*B1[n];
      y += h[n+4]*C1[n];
    }
    uptr[l*2048] = f2bf(y + Dpar*u);
  }
}

// ---------- final GEMM (prefetched): M=25088, N=512, K=2048, XCD-swizzled ----------
__global__ __launch_bounds__(256) void k_gemmF(const short* __restrict__ ycat,
    const short* __restrict__ wogc, const float* __restrict__ biasc,
    float* __restrict__ out)
{
  __shared__ __align__(16) short As[12288];   // 3 buffers x 8KB, [128 rows][4 slots x 8]
  __shared__ __align__(16) short Bs[12288];
  int bid = blockIdx.x;                       // 784 = 8 * 98, bijective XCD swizzle
  int swz = (bid & 7) * 98 + (bid >> 3);
  int bn = (swz & 3) * 128, bm = (swz >> 2) * 128;
  int tid = threadIdx.x, lane = tid & 63, wave = tid >> 6;

  const short* aG[2]; const short* bG[2]; int ldsOff[2];
  #pragma unroll
  for (int i = 0; i < 2; i++){
    int c = wave*2 + i;
    int r = c*16 + (lane >> 2);       // row within 128-tile (16 rows per instr)
    int ch = ((lane & 3) ^ ((lane >> 3) & 3)) * 8;   // pre-swizzled global chunk
    aG[i] = ycat + (size_t)(bm + r)*2048 + ch;
    bG[i] = wogc + (size_t)(bn + r)*2048 + ch;
    ldsOff[i] = c*512;
  }

  int mr = lane & 15, quad = lane >> 4;
  int wm = (wave & 1)*64, wn = (wave >> 1)*64;
  f32x4 acc[4][4] = {};

  kloop_pf<64>(aG[0], aG[1], bG[0], bG[1], ldsOff[0], ldsOff[1],
               As, Bs, quad, mr, wm, wn, acc);

  #pragma unroll
  for (int mt = 0; mt < 4; mt++)
    #pragma unroll
    for (int rr = 0; rr < 4; rr++){
      int row = bm + wm + mt*16 + quad*4 + rr;
      float* orow = out + (size_t)row*512;
      #pragma unroll
      for (int nt = 0; nt < 4; nt++){
        int col = bn + wn + nt*16 + mr;
        orow[col] = acc[mt][nt][rr] + biasc[col];
      }
    }
}

// ---------- launch ----------
extern "C" void kernel_launch(void* const* d_in, const int* in_sizes, int n_in,
                              void* d_out, int out_size, void* d_ws, size_t ws_size,
                              hipStream_t stream)
{
  const float* tokens    = (const float*)d_in[0];
  const float* pre_w[4]  = {(const float*)d_in[1], (const float*)d_in[3], (const float*)d_in[5], (const float*)d_in[7]};
  const float* pre_b[4]  = {(const float*)d_in[2], (const float*)d_in[4], (const float*)d_in[6], (const float*)d_in[8]};
  const float* post_w[4] = {(const float*)d_in[9], (const float*)d_in[11], (const float*)d_in[13], (const float*)d_in[15]};
  const float* post_b[4] = {(const float*)d_in[10], (const float*)d_in[12], (const float*)d_in[14], (const float*)d_in[16]};
  const float* in_proj   = (const float*)d_in[17];
  const float* conv_x_w  = (const float*)d_in[18];
  const float* conv_x_b  = (const float*)d_in[19];
  const float* conv_z_w  = (const float*)d_in[20];
  const float* conv_z_b  = (const float*)d_in[21];
  const float* x_proj_w  = (const float*)d_in[22];
  const float* ln_w      = (const float*)d_in[23];
  const float* ln_b      = (const float*)d_in[24];
  const float* dt_proj_w = (const float*)d_in[25];
  const float* dt_proj_b = (const float*)d_in[26];
  const float* A_log     = (const float*)d_in[27];
  const float* D_param   = (const float*)d_in[28];
  const float* out_proj  = (const float*)d_in[29];
  const float* gate_log  = (const float*)d_in[30];

  char* ws = (char*)d_ws;
  size_t o = 0;
  short* tok_bf   = (short*)(ws + o); o += 25690112;   // 12845056 bf16
  short* wpreT    = (short*)(ws + o); o += 2097152;    // 4x 512x512 bf16 (transposed)
  short* inp_bf   = (short*)(ws + o); o += 524288;
  short* postw_bf = (short*)(ws + o); o += 2097152;
  short* woutT    = (short*)(ws + o); o += 524288;
  short* wogc     = (short*)(ws + o); o += 2097152;    // 512 x 2048 bf16
  short* wxz      = (short*)(ws + o); o += 2097152;    // 4x 512x512 bf16
  short* xpw_bf   = (short*)(ws + o); o += 24576;      // 48x256 bf16
  short* dtw_bf   = (short*)(ws + o); o += 16384;      // 256x32 bf16
  float* bxz      = (float*)(ws + o); o += 8192;
  float* gains    = (float*)(ws + o); o += 64;
  float* biasc    = (float*)(ws + o); o += 2048;
  size_t xz_off = o;
  short* xz       = (short*)(ws + o); o += 102760448;  // 2048*49*512 bf16
  short* ycat     = (short*)(ws + o); o += 102760448;  // 25088 x 2048 bf16
  // dtln (51.4 MB) + bc (6.4 MB) alias the xz region: xz is dead after k_conv.
  short* dtln     = (short*)(ws + xz_off);
  float* bc       = (float*)(ws + xz_off + 51380224);

  k_conv_all<<<1300, 256, 0, stream>>>(in_proj,
      post_w[0], post_w[1], post_w[2], post_w[3],
      x_proj_w, dt_proj_w, inp_bf, postw_bf, xpw_bf, dtw_bf);
  k_transp<<<dim3(64,5), 256, 0, stream>>>(pre_w[0], pre_w[1], pre_w[2], pre_w[3],
      out_proj, wpreT, woutT);
  k_tok<<<12544, 256, 0, stream>>>(tokens, tok_bf);
  k_bxz_gains<<<9, 256, 0, stream>>>(in_proj, pre_b[0], pre_b[1], pre_b[2], pre_b[3],
      gate_log, post_b[0], post_b[1], post_b[2], post_b[3], bxz, gains, biasc);
  k_wfuse<<<dim3(8,4,8), 256, 0, stream>>>(inp_bf, wpreT, postw_bf, woutT, gains, wxz, wogc);
  k_gemm1<<<dim3(784,1,4), 256, 0, stream>>>(tok_bf, wxz, bxz, xz);
  k_conv<<<2048, 256, 0, stream>>>(xz, conv_x_w, conv_x_b, conv_z_w, conv_z_b, ycat);
  k_xproj<<<784, 256, 0, stream>>>(ycat, xpw_bf, ln_w, ln_b, dtw_bf, dt_proj_b, dtln, bc);
  k_scan<<<2048, 256, 0, stream>>>(ycat, dtln, bc, A_log, D_param);
  k_gemmF<<<dim3(784), 256, 0, stream>>>(ycat, wogc, biasc, (float*)d_out);
}

// Round 4
// 526.168 us; speedup vs baseline: 1.0016x; 1.0016x over previous
//
#include <hip/hip_runtime.h>
#include <stdint.h>

// ---------- types ----------
typedef __attribute__((ext_vector_type(8))) short bf16x8;   // 8 bf16 in 4 VGPRs
typedef __attribute__((ext_vector_type(4))) float f32x4;

__device__ __forceinline__ float bf2f(short u){
  union { float f; uint32_t i; } v; v.i = ((uint32_t)(uint16_t)u) << 16; return v.f;
}
__device__ __forceinline__ short f2bf(float x){
  union { float f; uint32_t i; } v; v.f = x;
  uint32_t r = v.i + 0x7FFFu + ((v.i >> 16) & 1u);   // RNE
  return (short)(r >> 16);
}

// async global->LDS, 16B per lane; LDS dest = wave-uniform base + lane*16
__device__ __forceinline__ void gl_lds16(const short* g, short* l){
  __builtin_amdgcn_global_load_lds(
      (__attribute__((address_space(1))) void*)(short*)g,
      (__attribute__((address_space(3))) void*)l, 16, 0, 0);
}

// ---------- permutation tables (WIN=7, compile-time) ----------
__device__ const int d_DIAG[49] = {0,1,7,2,8,14,3,9,15,21,4,10,16,22,28,5,11,17,23,29,35,
  6,12,18,24,30,36,42,13,19,25,31,37,43,20,26,32,38,44,27,33,39,45,34,40,46,41,47,48};
__device__ const int d_ANTI[49] = {6,5,13,4,12,20,3,11,19,27,2,10,18,26,34,1,9,17,25,33,41,
  0,8,16,24,32,40,48,7,15,23,31,39,47,14,22,30,38,46,21,29,37,45,28,36,44,35,43,42};

__device__ __forceinline__ int perm_idx(int g, int l){
  if (g == 0) return l;
  if (g == 1) return (l % 7) * 7 + l / 7;  // V_IDX
  if (g == 2) return d_DIAG[l];
  return d_ANTI[l];
}

// ---------- K-loop for BM=64 x BN=128, BK=32, 4 waves (2x2 of 32x64) ----------
// Combined LDS region per buffer: A rows 0..63 -> shorts [0,2048), B rows 0..127
// -> shorts [2048,6144). 2 buffers (24 KB total) -> 6 blocks/CU resident.
// Each wave stages 3 16-row x 64B chunks (wave-uniform LDS dest, per-lane global
// src pre-swizzled); 1-deep prefetch with counted vmcnt(3).
// Slot XOR-swizzle: LDS slot s of row r holds global chunk s ^ ((r>>1)&3);
// reads apply the same XOR -> ds_read_b128 conflict-free.
template<int NT>
__device__ __forceinline__ void kloop64(
    const short* g0, const short* g1, const short* g2,
    int l0, int l1, int l2, short* S,
    int quad, int mr, int wm, int wn, f32x4 acc[2][4])
{
  auto STAGE = [&](int t){
    int b = (t & 1) * 6144;
    gl_lds16(g0 + t*32, S + b + l0);
    gl_lds16(g1 + t*32, S + b + l1);
    gl_lds16(g2 + t*32, S + b + l2);
  };
  int sw = (quad ^ ((mr >> 1) & 3)) * 8;     // swizzled slot offset (shorts)
  STAGE(0);
  for (int t = 0; t < NT; ++t){
    if (t + 1 < NT){
      STAGE(t + 1);
      asm volatile("s_waitcnt vmcnt(3)" ::: "memory");   // tile t's 3 loads done
    } else {
      asm volatile("s_waitcnt vmcnt(0)" ::: "memory");
    }
    __builtin_amdgcn_s_barrier();            // all waves: tile t resident in LDS
    __builtin_amdgcn_sched_barrier(0);
    const short* Sb = S + (t & 1) * 6144;
    bf16x8 af[2], bfr[4];
    #pragma unroll
    for (int x = 0; x < 2; x++)
      af[x]  = *(const bf16x8*)(Sb + (wm + x*16 + mr)*32 + sw);
    #pragma unroll
    for (int x = 0; x < 4; x++)
      bfr[x] = *(const bf16x8*)(Sb + 2048 + (wn + x*16 + mr)*32 + sw);
    #pragma unroll
    for (int mt = 0; mt < 2; mt++)
      #pragma unroll
      for (int nt2 = 0; nt2 < 4; nt2++)
        acc[mt][nt2] = __builtin_amdgcn_mfma_f32_16x16x32_bf16(af[mt], bfr[nt2], acc[mt][nt2],0,0,0);
    __builtin_amdgcn_sched_barrier(0);
    __builtin_amdgcn_s_barrier();            // all waves done reading buf (t&1)
  }
}

// ---------- prep: plain f32->bf16 converts (in_proj, post x4, x_proj_w, dt_proj_w) ----------
__global__ __launch_bounds__(256) void k_conv_all(
    const float* __restrict__ in_proj,
    const float* __restrict__ pw0, const float* __restrict__ pw1,
    const float* __restrict__ pw2, const float* __restrict__ pw3,
    const float* __restrict__ xpw, const float* __restrict__ dtw,
    short* __restrict__ inp_bf, short* __restrict__ postw_bf,
    short* __restrict__ xpw_bf, short* __restrict__ dtw_bf)
{
  int q = blockIdx.x*256 + threadIdx.x;   // quad index, total 332800
  const float* src; short* dst; int off;
  if (q < 65536){ src = in_proj; dst = inp_bf; off = q; }
  else if (q < 65536 + 262144){
    int r = q - 65536; int g = r >> 16; int loc = r & 65535;
    src = (g==0)?pw0:(g==1)?pw1:(g==2)?pw2:pw3;
    dst = postw_bf + g*262144; off = loc;
  }
  else if (q < 65536 + 262144 + 3072){ src = xpw; dst = xpw_bf; off = q - (65536+262144); }
  else { src = dtw; dst = dtw_bf; off = q - (65536+262144+3072); }
  float4 v = *(const float4*)(src + off*4);
  uint32_t p0 = (uint32_t)(uint16_t)f2bf(v.x) | ((uint32_t)(uint16_t)f2bf(v.y) << 16);
  uint32_t p1 = (uint32_t)(uint16_t)f2bf(v.z) | ((uint32_t)(uint16_t)f2bf(v.w) << 16);
  uint2 p; p.x = p0; p.y = p1;
  *(uint2*)(dst + off*4) = p;
}

// ---------- prep: LDS-tiled transpose+convert (pre_w x4 -> wpreT, out_proj -> woutT) ----------
__global__ __launch_bounds__(256) void k_transp(
    const float* __restrict__ pw0, const float* __restrict__ pw1,
    const float* __restrict__ pw2, const float* __restrict__ pw3,
    const float* __restrict__ outp,
    short* __restrict__ wpreT, short* __restrict__ woutT)
{
  __shared__ float tile[64][65];
  int which = blockIdx.y;
  const float* src = (which==0)?pw0:(which==1)?pw1:(which==2)?pw2:(which==3)?pw3:outp;
  short* dst = (which < 4) ? (wpreT + which*262144) : woutT;
  int bi = blockIdx.x >> 3, bj = blockIdx.x & 7;
  int r0 = bi*64, c0 = bj*64;
  int t = threadIdx.x;
  int row = t >> 2, cg = t & 3;
  const float4* s4 = (const float4*)(src + (r0+row)*512 + c0 + cg*16);
  #pragma unroll
  for (int i=0;i<4;i++){
    float4 v = s4[i];
    tile[row][cg*16 + i*4 + 0] = v.x;
    tile[row][cg*16 + i*4 + 1] = v.y;
    tile[row][cg*16 + i*4 + 2] = v.z;
    tile[row][cg*16 + i*4 + 3] = v.w;
  }
  __syncthreads();
  int oc = t >> 2;
  short tmp[16];
  #pragma unroll
  for (int i=0;i<16;i++) tmp[i] = f2bf(tile[cg*16 + i][oc]);
  short* dp = dst + (size_t)(c0+oc)*512 + r0 + cg*16;
  *(bf16x8*)(dp)     = *(bf16x8*)tmp;
  *(bf16x8*)(dp + 8) = *((bf16x8*)tmp + 1);
}

__global__ __launch_bounds__(256) void k_tok(const float* __restrict__ t, short* __restrict__ o){
  int i = (blockIdx.x*256 + threadIdx.x) * 4;
  float4 v = *(const float4*)(t + i);
  uint32_t p0 = (uint32_t)(uint16_t)f2bf(v.x) | ((uint32_t)(uint16_t)f2bf(v.y) << 16);
  uint32_t p1 = (uint32_t)(uint16_t)f2bf(v.z) | ((uint32_t)(uint16_t)f2bf(v.w) << 16);
  uint2 p; p.x = p0; p.y = p1;
  *(uint2*)(o + i) = p;
}

// ---------- prep: b_xz (blocks 0-7) + gains/biasc (block 8) ----------
__global__ __launch_bounds__(256) void k_bxz_gains(const float* __restrict__ in_proj,
    const float* __restrict__ b0, const float* __restrict__ b1,
    const float* __restrict__ b2, const float* __restrict__ b3,
    const float* __restrict__ gl,
    const float* __restrict__ pb0, const float* __restrict__ pb1,
    const float* __restrict__ pb2, const float* __restrict__ pb3,
    float* __restrict__ bxz, float* __restrict__ gains, float* __restrict__ biasc)
{
  if (blockIdx.x < 8){
    int idx = blockIdx.x*256 + threadIdx.x;   // 0..2047
    int g = idx >> 9, i = idx & 511;
    const float* bb = (g==0)?b0:(g==1)?b1:(g==2)?b2:b3;
    float s = 0.f;
    for (int t=0;t<512;t++) s += in_proj[i*512+t]*bb[t];
    bxz[idx] = s;
  } else {
    float m = fmaxf(fmaxf(gl[0], gl[1]), fmaxf(gl[2], gl[3]));
    float e0 = expf(gl[0]-m), e1 = expf(gl[1]-m), e2 = expf(gl[2]-m), e3 = expf(gl[3]-m);
    float s = e0+e1+e2+e3;
    float g0 = e0/s, g1 = e1/s, g2 = e2/s, g3 = e3/s;
    int t = threadIdx.x;
    if (t == 0){ gains[0]=g0; gains[1]=g1; gains[2]=g2; gains[3]=g3; }
    biasc[t]     = g0*pb0[t]     + g1*pb1[t]     + g2*pb2[t]     + g3*pb3[t];
    biasc[t+256] = g0*pb0[t+256] + g1*pb1[t+256] + g2*pb2[t+256] + g3*pb3[t+256];
  }
}

// ---------- register-GEMM core for the tiny weight-fuse GEMMs ----------
__device__ __forceinline__ void mfma_2x4_k(const short* a0, const short* a1,
    const short* b0, const short* b1, const short* b2, const short* b3,
    int K, f32x4 acc[2][4])
{
  for (int k0 = 0; k0 < K; k0 += 32){
    bf16x8 av0 = *(const bf16x8*)(a0 + k0);
    bf16x8 av1 = *(const bf16x8*)(a1 + k0);
    bf16x8 bv0 = *(const bf16x8*)(b0 + k0);
    bf16x8 bv1 = *(const bf16x8*)(b1 + k0);
    bf16x8 bv2 = *(const bf16x8*)(b2 + k0);
    bf16x8 bv3 = *(const bf16x8*)(b3 + k0);
    acc[0][0] = __builtin_amdgcn_mfma_f32_16x16x32_bf16(av0, bv0, acc[0][0],0,0,0);
    acc[0][1] = __builtin_amdgcn_mfma_f32_16x16x32_bf16(av0, bv1, acc[0][1],0,0,0);
    acc[0][2] = __builtin_amdgcn_mfma_f32_16x16x32_bf16(av0, bv2, acc[0][2],0,0,0);
    acc[0][3] = __builtin_amdgcn_mfma_f32_16x16x32_bf16(av0, bv3, acc[0][3],0,0,0);
    acc[1][0] = __builtin_amdgcn_mfma_f32_16x16x32_bf16(av1, bv0, acc[1][0],0,0,0);
    acc[1][1] = __builtin_amdgcn_mfma_f32_16x16x32_bf16(av1, bv1, acc[1][1],0,0,0);
    acc[1][2] = __builtin_amdgcn_mfma_f32_16x16x32_bf16(av1, bv2, acc[1][2],0,0,0);
    acc[1][3] = __builtin_amdgcn_mfma_f32_16x16x32_bf16(av1, bv3, acc[1][3],0,0,0);
  }
}

// ---------- merged weight-fuse: z<4 -> W_xz[g]; z>=4 -> Wog[g] ----------
__global__ __launch_bounds__(256) void k_wfuse(const short* __restrict__ inp_bf,
    const short* __restrict__ wpreT, const short* __restrict__ postw_bf,
    const short* __restrict__ woutT, const float* __restrict__ gains,
    short* __restrict__ wxz, short* __restrict__ wogc)
{
  int z = blockIdx.z; int g = z & 3, which = z >> 2;
  int bn = blockIdx.x * 64, bm = blockIdx.y * 128;
  int lane = threadIdx.x & 63, wave = threadIdx.x >> 6;
  int mr = lane & 15, qk = (lane >> 4) * 8, quad = lane >> 4;
  const short* Am = which ? (postw_bf + g*262144) : inp_bf;
  const short* Bm = which ? woutT : (wpreT + g*262144);
  const short* a0 = Am + (bm + wave*32 + mr)*512 + qk;
  const short* a1 = a0 + 16*512;
  const short* b0 = Bm + (bn +  0 + mr)*512 + qk;
  const short* b1 = Bm + (bn + 16 + mr)*512 + qk;
  const short* b2 = Bm + (bn + 32 + mr)*512 + qk;
  const short* b3 = Bm + (bn + 48 + mr)*512 + qk;
  f32x4 acc[2][4] = {};
  mfma_2x4_k(a0, a1, b0, b1, b2, b3, 512, acc);
  float gain = which ? gains[g] : 1.f;
  #pragma unroll
  for (int s=0;s<2;s++)
    #pragma unroll
    for (int t=0;t<4;t++)
      #pragma unroll
      for (int r=0;r<4;r++){
        int row = bm + wave*32 + s*16 + quad*4 + r;
        int col = bn + t*16 + mr;
        if (which) wogc[row*2048 + g*512 + col] = f2bf(gain * acc[s][t][r]);
        else       wxz[g*262144 + row*512 + col] = f2bf(acc[s][t][r]);
      }
}

// ---------- GEMM1: BM=64, BN=128, BK=32, K=512, grid (1568,1,4), XCD-swizzled ----------
// xz[(g*512+b)*49+l][ch] = tok[b][perm_g(l)][:] @ W_xz[g]^T + b_xz[g]
__global__ __launch_bounds__(256) void k_gemm1(const short* __restrict__ tok,
    const short* __restrict__ wxz, const float* __restrict__ bxz, short* __restrict__ xz)
{
  __shared__ __align__(16) short S[12288];    // 2 buffers x (A 64x32 | B 128x32)
  int g = blockIdx.z;
  int bid = blockIdx.x;                       // 1568 = 8 * 196, bijective XCD swizzle
  int swz = (bid & 7) * 196 + (bid >> 3);
  int bn = (swz & 3) * 128, bm = (swz >> 2) * 64;
  int tid = threadIdx.x, lane = tid & 63, wave = tid >> 6;

  const short* gp[3]; int lo[3];
  {
    int rr16 = lane >> 2;                      // row within 16-row chunk
    int ch = ((lane & 3) ^ ((lane >> 3) & 3)) * 8;   // pre-swizzled global chunk
    #pragma unroll
    for (int i = 0; i < 3; i++){
      int c = wave*3 + i;                      // chunk 0..11 (A:0-3, B:4-11)
      if (c < 4){
        int grow = bm + c*16 + rr16;
        int b = grow / 49, l = grow - b*49;
        int sl = perm_idx(g, l);
        gp[i] = tok + ((size_t)(b*49 + sl))*512 + ch;
        lo[i] = c*512;
      } else {
        gp[i] = wxz + (size_t)g*262144 + (size_t)(bn + (c-4)*16 + rr16)*512 + ch;
        lo[i] = 2048 + (c-4)*512;
      }
    }
  }

  int mr = lane & 15, quad = lane >> 4;
  int wm = (wave & 1)*32, wn = (wave >> 1)*64;
  f32x4 acc[2][4] = {};

  kloop64<16>(gp[0], gp[1], gp[2], lo[0], lo[1], lo[2], S, quad, mr, wm, wn, acc);

  #pragma unroll
  for (int mt = 0; mt < 2; mt++)
    #pragma unroll
    for (int rr = 0; rr < 4; rr++){
      int row = bm + wm + mt*16 + quad*4 + rr;
      int b = row / 49, l = row - b*49;
      size_t orow = ((size_t)(g*512 + b)*49 + l)*512;
      #pragma unroll
      for (int nt = 0; nt < 4; nt++){
        int col = bn + wn + nt*16 + mr;
        xz[orow + col] = f2bf(acc[mt][nt][rr] + bxz[g*512 + col]);
      }
    }
}

// ---------- k_conv: depthwise conv3 + SiLU, fully parallel ----------
__global__ __launch_bounds__(256) void k_conv(const short* __restrict__ xz,
    const float* __restrict__ cxw, const float* __restrict__ cxb,
    const float* __restrict__ czw, const float* __restrict__ czb,
    short* __restrict__ ycat)
{
  int t = threadIdx.x;
  int oct = t & 63, lstart = t >> 6;
  int ch0 = oct * 8;
  bool isx = ch0 < 256;
  int cc0 = isx ? ch0 : ch0 - 256;
  const float* wsrc = isx ? cxw : czw;
  const float* bsrc = isx ? cxb : czb;
  float w0[8], w1[8], w2[8], bb[8];
  #pragma unroll
  for (int e=0;e<8;e++){
    w0[e] = wsrc[(cc0+e)*3]; w1[e] = wsrc[(cc0+e)*3+1]; w2[e] = wsrc[(cc0+e)*3+2];
    bb[e] = bsrc[cc0+e];
  }
  int gb = blockIdx.x; int g = gb >> 9, b = gb & 511;
  const short* src = xz + (size_t)gb*25088 + ch0;
  short* dst = ycat + (size_t)(b*49)*2048 + g*512 + ch0;
  for (int l = lstart; l < 49; l += 4){
    bf16x8 vm = {}, vp = {};
    bf16x8 v0 = *(const bf16x8*)(src + l*512);
    if (l > 0)  vm = *(const bf16x8*)(src + (l-1)*512);
    if (l < 48) vp = *(const bf16x8*)(src + (l+1)*512);
    short ov[8];
    #pragma unroll
    for (int e=0;e<8;e++){
      float x = w0[e]*bf2f(vm[e]) + w1[e]*bf2f(v0[e]) + w2[e]*bf2f(vp[e]) + bb[e];
      ov[e] = f2bf(x / (1.f + __expf(-x)));
    }
    *(bf16x8*)(dst + l*2048) = *(bf16x8*)ov;
  }
}

// ---------- k_xproj: x_proj GEMM + LN + dt GEMM + softplus ----------
__global__ __launch_bounds__(256) void k_xproj(const short* __restrict__ ycat,
    const short* __restrict__ xpw_bf, const float* __restrict__ lnw, const float* __restrict__ lnb,
    const short* __restrict__ dtw_bf, const float* __restrict__ dtb,
    short* __restrict__ dtln, float* __restrict__ bc)
{
  // LDS: xd f32 [128][52] = 26624 B ; xln_bf bf16 [128][40] = 10240 B
  __shared__ __align__(16) char smem[36864];
  float* xd = (float*)smem;
  short* xln = (short*)(smem + 26624);

  int bm = blockIdx.x * 128;
  int g = bm / 25088;                   // uniform per block (128 | 25088)
  int tid = threadIdx.x, lane = tid & 63, w = tid >> 6;
  int mr = lane & 15, quad = lane >> 4, qk = quad * 8;

  // ---- phase 1: x_dbl = u @ xpw^T  (tile 128x48, K=256) ----
  {
    const short* ap[2];
    #pragma unroll
    for (int s=0;s<2;s++)
      ap[s] = ycat + (size_t)(bm - g*25088 + w*32 + s*16 + mr)*2048 + g*512 + qk;
    f32x4 acc[2][3] = {};
    #pragma unroll
    for (int k0 = 0; k0 < 256; k0 += 32){
      bf16x8 av[2];
      #pragma unroll
      for (int s=0;s<2;s++) av[s] = *(const bf16x8*)(ap[s] + k0);
      #pragma unroll
      for (int t=0;t<3;t++){
        bf16x8 bv = *(const bf16x8*)(xpw_bf + (t*16 + mr)*256 + qk + k0);
        #pragma unroll
        for (int s=0;s<2;s++)
          acc[s][t] = __builtin_amdgcn_mfma_f32_16x16x32_bf16(av[s], bv, acc[s][t],0,0,0);
      }
    }
    #pragma unroll
    for (int s=0;s<2;s++)
      #pragma unroll
      for (int t=0;t<3;t++)
        #pragma unroll
        for (int r=0;r<4;r++)
          xd[(w*32 + s*16 + quad*4 + r)*52 + t*16 + mr] = acc[s][t][r];
  }
  __syncthreads();

  // ---- phase 2: LN per row (threads 0..127), write dt-cols to xln (bf16) + B/C to global ----
  if (tid < 128){
    f32x4* xr4 = (f32x4*)(xd + tid*52);
    f32x4 s = xr4[0];
    #pragma unroll
    for (int i=1;i<12;i++) s += xr4[i];
    float m = (s[0]+s[1]+s[2]+s[3]) * (1.f/48.f);
    f32x4 vs = {};
    #pragma unroll
    for (int i=0;i<12;i++){ f32x4 d = xr4[i] - m; vs += d*d; }
    float var = (vs[0]+vs[1]+vs[2]+vs[3]) * (1.f/48.f);
    float rstd = rsqrtf(var + 1e-5f);
    const f32x4* g4 = (const f32x4*)lnw;
    const f32x4* b4 = (const f32x4*)lnb;
    uint32_t* xlr = (uint32_t*)(xln + tid*40);
    #pragma unroll
    for (int i=0;i<8;i++){       // cols 0..31 -> xln bf16
      f32x4 v = (xr4[i] - m) * rstd * g4[i] + b4[i];
      xlr[2*i]   = (uint32_t)(uint16_t)f2bf(v[0]) | ((uint32_t)(uint16_t)f2bf(v[1]) << 16);
      xlr[2*i+1] = (uint32_t)(uint16_t)f2bf(v[2]) | ((uint32_t)(uint16_t)f2bf(v[3]) << 16);
    }
    f32x4* bco = (f32x4*)(bc + (size_t)(bm + tid)*16);
    #pragma unroll
    for (int i=8;i<12;i++)       // cols 32..47 -> bc f32
      bco[i-8] = (xr4[i] - m) * rstd * g4[i] + b4[i];
  }
  __syncthreads();

  // ---- phase 3: dt = xln[:,0:32] @ dtw^T (K=32, N=256) + bias + softplus -> dtln ----
  // softplus via hardware exp2/log2 path; for x>15 select x (err << bf16 ulp).
  {
    bf16x8 a[2];
    #pragma unroll
    for (int s=0;s<2;s++)
      a[s] = *(const bf16x8*)(xln + (w*32 + s*16 + mr)*40 + qk);
    #pragma unroll 4
    for (int nt=0; nt<16; nt++){
      int col = nt*16 + mr;
      bf16x8 bv = *(const bf16x8*)(dtw_bf + col*32 + qk);
      float dtbv = dtb[col];
      #pragma unroll
      for (int s=0;s<2;s++){
        f32x4 acc = {};
        acc = __builtin_amdgcn_mfma_f32_16x16x32_bf16(a[s], bv, acc,0,0,0);
        #pragma unroll
        for (int r=0;r<4;r++){
          int grow = bm + w*32 + s*16 + quad*4 + r;
          float dtv = acc[r] + dtbv;
          float e  = __expf(dtv);
          float sp = __logf(1.f + e);
          float delta = (dtv > 15.f) ? dtv : sp;
          dtln[(size_t)grow*256 + col] = f2bf(delta);
        }
      }
    }
  }
}

// ---------- k_scan: selective scan, one block per gb, u->y in place ----------
__global__ __launch_bounds__(256) void k_scan(short* __restrict__ ycat,
    const short* __restrict__ dtln, const float* __restrict__ bc,
    const float* __restrict__ Alog, const float* __restrict__ Dp)
{
  __shared__ __align__(16) float bcs[784];   // [49][16]
  int gb = blockIdx.x; int g = gb >> 9, b = gb & 511;
  int d = threadIdx.x;
  if (d < 196) ((f32x4*)bcs)[d] = ((const f32x4*)(bc + (size_t)gb*784))[d];
  __syncthreads();

  float A[8], h[8];
  {
    f32x4 a0 = *(const f32x4*)(Alog + d*8);
    f32x4 a1 = *(const f32x4*)(Alog + d*8 + 4);
    #pragma unroll
    for (int n=0;n<4;n++){ A[n] = -__expf(a0[n]); A[n+4] = -__expf(a1[n]); h[n]=0.f; h[n+4]=0.f; }
  }
  float Dpar = Dp[d];

  const short* dptr = dtln + (size_t)gb*49*256 + d;
  short* uptr = ycat + (size_t)(b*49)*2048 + g*512 + d;

  float dn = bf2f(dptr[0]);
  float un = bf2f(uptr[0]);
  for (int l=0;l<49;l++){
    float delta = dn, u = un;
    if (l < 48){ dn = bf2f(dptr[(l+1)*256]); un = bf2f(uptr[(l+1)*2048]); }
    const f32x4* bcr = (const f32x4*)(bcs + l*16);
    f32x4 B0 = bcr[0], B1 = bcr[1], C0 = bcr[2], C1 = bcr[3];
    float du = delta * u;
    float y = 0.f;
    #pragma unroll
    for (int n=0;n<4;n++){
      h[n] = h[n]*__expf(delta*A[n]) + du*B0[n];
      y += h[n]*C0[n];
    }
    #pragma unroll
    for (int n=0;n<4;n++){
      h[n+4] = h[n+4]*__expf(delta*A[n+4]) + du*B1[n];
      y += h[n+4]*C1[n];
    }
    uptr[l*2048] = f2bf(y + Dpar*u);
  }
}

// ---------- final GEMM: BM=64, BN=128, BK=32, K=2048, grid 1568, XCD-swizzled ----------
__global__ __launch_bounds__(256) void k_gemmF(const short* __restrict__ ycat,
    const short* __restrict__ wogc, const float* __restrict__ biasc,
    float* __restrict__ out)
{
  __shared__ __align__(16) short S[12288];    // 2 buffers x (A 64x32 | B 128x32)
  int bid = blockIdx.x;                       // 1568 = 8 * 196, bijective XCD swizzle
  int swz = (bid & 7) * 196 + (bid >> 3);
  int bn = (swz & 3) * 128, bm = (swz >> 2) * 64;
  int tid = threadIdx.x, lane = tid & 63, wave = tid >> 6;

  const short* gp[3]; int lo[3];
  {
    int rr16 = lane >> 2;
    int ch = ((lane & 3) ^ ((lane >> 3) & 3)) * 8;   // pre-swizzled global chunk
    #pragma unroll
    for (int i = 0; i < 3; i++){
      int c = wave*3 + i;                      // chunk 0..11 (A:0-3, B:4-11)
      if (c < 4){
        gp[i] = ycat + (size_t)(bm + c*16 + rr16)*2048 + ch;
        lo[i] = c*512;
      } else {
        gp[i] = wogc + (size_t)(bn + (c-4)*16 + rr16)*2048 + ch;
        lo[i] = 2048 + (c-4)*512;
      }
    }
  }

  int mr = lane & 15, quad = lane >> 4;
  int wm = (wave & 1)*32, wn = (wave >> 1)*64;
  f32x4 acc[2][4] = {};

  kloop64<64>(gp[0], gp[1], gp[2], lo[0], lo[1], lo[2], S, quad, mr, wm, wn, acc);

  #pragma unroll
  for (int mt = 0; mt < 2; mt++)
    #pragma unroll
    for (int rr = 0; rr < 4; rr++){
      int row = bm + wm + mt*16 + quad*4 + rr;
      float* orow = out + (size_t)row*512;
      #pragma unroll
      for (int nt = 0; nt < 4; nt++){
        int col = bn + wn + nt*16 + mr;
        orow[col] = acc[mt][nt][rr] + biasc[col];
      }
    }
}

// ---------- launch ----------
extern "C" void kernel_launch(void* const* d_in, const int* in_sizes, int n_in,
                              void* d_out, int out_size, void* d_ws, size_t ws_size,
                              hipStream_t stream)
{
  const float* tokens    = (const float*)d_in[0];
  const float* pre_w[4]  = {(const float*)d_in[1], (const float*)d_in[3], (const float*)d_in[5], (const float*)d_in[7]};
  const float* pre_b[4]  = {(const float*)d_in[2], (const float*)d_in[4], (const float*)d_in[6], (const float*)d_in[8]};
  const float* post_w[4] = {(const float*)d_in[9], (const float*)d_in[11], (const float*)d_in[13], (const float*)d_in[15]};
  const float* post_b[4] = {(const float*)d_in[10], (const float*)d_in[12], (const float*)d_in[14], (const float*)d_in[16]};
  const float* in_proj   = (const float*)d_in[17];
  const float* conv_x_w  = (const float*)d_in[18];
  const float* conv_x_b  = (const float*)d_in[19];
  const float* conv_z_w  = (const float*)d_in[20];
  const float* conv_z_b  = (const float*)d_in[21];
  const float* x_proj_w  = (const float*)d_in[22];
  const float* ln_w      = (const float*)d_in[23];
  const float* ln_b      = (const float*)d_in[24];
  const float* dt_proj_w = (const float*)d_in[25];
  const float* dt_proj_b = (const float*)d_in[26];
  const float* A_log     = (const float*)d_in[27];
  const float* D_param   = (const float*)d_in[28];
  const float* out_proj  = (const float*)d_in[29];
  const float* gate_log  = (const float*)d_in[30];

  char* ws = (char*)d_ws;
  size_t o = 0;
  short* tok_bf   = (short*)(ws + o); o += 25690112;   // 12845056 bf16
  short* wpreT    = (short*)(ws + o); o += 2097152;    // 4x 512x512 bf16 (transposed)
  short* inp_bf   = (short*)(ws + o); o += 524288;
  short* postw_bf = (short*)(ws + o); o += 2097152;
  short* woutT    = (short*)(ws + o); o += 524288;
  short* wogc     = (short*)(ws + o); o += 2097152;    // 512 x 2048 bf16
  short* wxz      = (short*)(ws + o); o += 2097152;    // 4x 512x512 bf16
  short* xpw_bf   = (short*)(ws + o); o += 24576;      // 48x256 bf16
  short* dtw_bf   = (short*)(ws + o); o += 16384;      // 256x32 bf16
  float* bxz      = (float*)(ws + o); o += 8192;
  float* gains    = (float*)(ws + o); o += 64;
  float* biasc    = (float*)(ws + o); o += 2048;
  size_t xz_off = o;
  short* xz       = (short*)(ws + o); o += 102760448;  // 2048*49*512 bf16
  short* ycat     = (short*)(ws + o); o += 102760448;  // 25088 x 2048 bf16
  // dtln (51.4 MB) + bc (6.4 MB) alias the xz region: xz is dead after k_conv.
  short* dtln     = (short*)(ws + xz_off);
  float* bc       = (float*)(ws + xz_off + 51380224);

  k_conv_all<<<1300, 256, 0, stream>>>(in_proj,
      post_w[0], post_w[1], post_w[2], post_w[3],
      x_proj_w, dt_proj_w, inp_bf, postw_bf, xpw_bf, dtw_bf);
  k_transp<<<dim3(64,5), 256, 0, stream>>>(pre_w[0], pre_w[1], pre_w[2], pre_w[3],
      out_proj, wpreT, woutT);
  k_tok<<<12544, 256, 0, stream>>>(tokens, tok_bf);
  k_bxz_gains<<<9, 256, 0, stream>>>(in_proj, pre_b[0], pre_b[1], pre_b[2], pre_b[3],
      gate_log, post_b[0], post_b[1], post_b[2], post_b[3], bxz, gains, biasc);
  k_wfuse<<<dim3(8,4,8), 256, 0, stream>>>(inp_bf, wpreT, postw_bf, woutT, gains, wxz, wogc);
  k_gemm1<<<dim3(1568,1,4), 256, 0, stream>>>(tok_bf, wxz, bxz, xz);
  k_conv<<<2048, 256, 0, stream>>>(xz, conv_x_w, conv_x_b, conv_z_w, conv_z_b, ycat);
  k_xproj<<<784, 256, 0, stream>>>(ycat, xpw_bf, ln_w, ln_b, dtw_bf, dt_proj_b, dtln, bc);
  k_scan<<<2048, 256, 0, stream>>>(ycat, dtln, bc, A_log, D_param);
  k_gemmF<<<dim3(1568), 256, 0, stream>>>(ycat, wogc, biasc, (float*)d_out);
}

// Round 5
// 513.119 us; speedup vs baseline: 1.0271x; 1.0254x over previous
//
#include <hip/hip_runtime.h>
#include <stdint.h>

// ---------- types ----------
typedef __attribute__((ext_vector_type(8))) short bf16x8;   // 8 bf16 in 4 VGPRs
typedef __attribute__((ext_vector_type(4))) float f32x4;

__device__ __forceinline__ float bf2f(short u){
  union { float f; uint32_t i; } v; v.i = ((uint32_t)(uint16_t)u) << 16; return v.f;
}
__device__ __forceinline__ short f2bf(float x){
  union { float f; uint32_t i; } v; v.f = x;
  uint32_t r = v.i + 0x7FFFu + ((v.i >> 16) & 1u);   // RNE
  return (short)(r >> 16);
}

// async global->LDS, 16B per lane; LDS dest = wave-uniform base + lane*16
__device__ __forceinline__ void gl_lds16(const short* g, short* l){
  __builtin_amdgcn_global_load_lds(
      (__attribute__((address_space(1))) void*)(short*)g,
      (__attribute__((address_space(3))) void*)l, 16, 0, 0);
}

// ---------- permutation tables (WIN=7, compile-time) ----------
__device__ const int d_DIAG[49] = {0,1,7,2,8,14,3,9,15,21,4,10,16,22,28,5,11,17,23,29,35,
  6,12,18,24,30,36,42,13,19,25,31,37,43,20,26,32,38,44,27,33,39,45,34,40,46,41,47,48};
__device__ const int d_ANTI[49] = {6,5,13,4,12,20,3,11,19,27,2,10,18,26,34,1,9,17,25,33,41,
  0,8,16,24,32,40,48,7,15,23,31,39,47,14,22,30,38,46,21,29,37,45,28,36,44,35,43,42};

__device__ __forceinline__ int perm_idx(int g, int l){
  if (g == 0) return l;
  if (g == 1) return (l % 7) * 7 + l / 7;  // V_IDX
  if (g == 2) return d_DIAG[l];
  return d_ANTI[l];
}

// ---------- 256x256 K-loop core: BK=32, 8 waves (2M x 4N), counted vmcnt ----------
// LDS (shorts): buf c at c*16384: A [256 rows][4 chunks of 8] at +0 (8192),
// B same at +8192. Row stride 32 shorts (64B). Chunk XOR-swizzle (proven r2/r3):
// LDS chunk s of row r holds global chunk s ^ ((r>>1)&3); reads use
// quad ^ ((mr>>1)&3) -> conflict-free ds_read_b128.
// Per wave per tile: 4 stage units of 16 rows x 64B (A0,A1,B0,B1).
// Schedule: boundary stages A-units of t+2 then waits vmcnt(2) (= all of t+1
// landed, 2 of t+2 in flight; no mid-loop drain); B-units of t+1 staged inside
// the phase loop of tile t (their dest buffer (t+1)&1 is not being read).
// Barriers: 2 per tile (reads-done before overwrite; t+1 data visible).
template<int NT>
__device__ __forceinline__ void kcore256(
    const short* aU0, const short* aU1, const short* bU0, const short* bU1,
    short* S, int w, int lane, f32x4 acc[8][4])
{
  int wr = w >> 2, wc = w & 3;
  int mr = lane & 15, quad = lane >> 4;
  int sw = (quad ^ ((mr >> 1) & 3)) * 8;     // swizzled chunk offset (shorts)
  auto STAGE = [&](int u, int t){
    short* base = S + (t & 1) * 16384;
    if      (u == 0) gl_lds16(aU0 + t*32, base + (w*32)*32);
    else if (u == 1) gl_lds16(aU1 + t*32, base + (w*32 + 16)*32);
    else if (u == 2) gl_lds16(bU0 + t*32, base + 8192 + (w*32)*32);
    else             gl_lds16(bU1 + t*32, base + 8192 + (w*32 + 16)*32);
  };
  STAGE(0,0); STAGE(1,0); STAGE(2,0); STAGE(3,0);
  if (NT > 1){ STAGE(0,1); STAGE(1,1); }
  asm volatile("s_waitcnt vmcnt(2)" ::: "memory");
  __builtin_amdgcn_s_barrier();
  for (int t = 0; t < NT; ++t){
    const short* Ab = S + (t & 1) * 16384;
    const short* Bb = Ab + 8192;
    bf16x8 bfr[4];
    #pragma unroll
    for (int nf = 0; nf < 4; ++nf)
      bfr[nf] = *(const bf16x8*)(Bb + (wc*64 + nf*16 + mr)*32 + sw);
    #pragma unroll
    for (int ph = 0; ph < 4; ++ph){
      bf16x8 af[2];
      #pragma unroll
      for (int mi = 0; mi < 2; ++mi)
        af[mi] = *(const bf16x8*)(Ab + (wr*128 + (ph*2+mi)*16 + mr)*32 + sw);
      if (ph < 2 && t+1 < NT) STAGE(2+ph, t+1);   // B-units of t+1 -> buf (t+1)&1
      #pragma unroll
      for (int mi = 0; mi < 2; ++mi)
        #pragma unroll
        for (int nf = 0; nf < 4; ++nf)
          acc[ph*2+mi][nf] = __builtin_amdgcn_mfma_f32_16x16x32_bf16(af[mi], bfr[nf], acc[ph*2+mi][nf],0,0,0);
    }
    __builtin_amdgcn_s_barrier();            // all waves done reading buf t&1
    if (t+2 < NT){
      STAGE(0, t+2); STAGE(1, t+2);          // A-units of t+2 -> just-freed buf
      asm volatile("s_waitcnt vmcnt(2)" ::: "memory");   // all of t+1 landed
    } else if (t+1 < NT){
      asm volatile("s_waitcnt vmcnt(0)" ::: "memory");   // tail drain (once)
    }
    __builtin_amdgcn_s_barrier();            // all waves' t+1 loads visible
  }
}

// ---------- prep: plain f32->bf16 converts (in_proj, post x4, x_proj_w, dt_proj_w) ----------
__global__ __launch_bounds__(256) void k_conv_all(
    const float* __restrict__ in_proj,
    const float* __restrict__ pw0, const float* __restrict__ pw1,
    const float* __restrict__ pw2, const float* __restrict__ pw3,
    const float* __restrict__ xpw, const float* __restrict__ dtw,
    short* __restrict__ inp_bf, short* __restrict__ postw_bf,
    short* __restrict__ xpw_bf, short* __restrict__ dtw_bf)
{
  int q = blockIdx.x*256 + threadIdx.x;   // quad index, total 332800
  const float* src; short* dst; int off;
  if (q < 65536){ src = in_proj; dst = inp_bf; off = q; }
  else if (q < 65536 + 262144){
    int r = q - 65536; int g = r >> 16; int loc = r & 65535;
    src = (g==0)?pw0:(g==1)?pw1:(g==2)?pw2:pw3;
    dst = postw_bf + g*262144; off = loc;
  }
  else if (q < 65536 + 262144 + 3072){ src = xpw; dst = xpw_bf; off = q - (65536+262144); }
  else { src = dtw; dst = dtw_bf; off = q - (65536+262144+3072); }
  float4 v = *(const float4*)(src + off*4);
  uint32_t p0 = (uint32_t)(uint16_t)f2bf(v.x) | ((uint32_t)(uint16_t)f2bf(v.y) << 16);
  uint32_t p1 = (uint32_t)(uint16_t)f2bf(v.z) | ((uint32_t)(uint16_t)f2bf(v.w) << 16);
  uint2 p; p.x = p0; p.y = p1;
  *(uint2*)(dst + off*4) = p;
}

// ---------- prep: LDS-tiled transpose+convert (pre_w x4 -> wpreT, out_proj -> woutT) ----------
__global__ __launch_bounds__(256) void k_transp(
    const float* __restrict__ pw0, const float* __restrict__ pw1,
    const float* __restrict__ pw2, const float* __restrict__ pw3,
    const float* __restrict__ outp,
    short* __restrict__ wpreT, short* __restrict__ woutT)
{
  __shared__ float tile[64][65];
  int which = blockIdx.y;
  const float* src = (which==0)?pw0:(which==1)?pw1:(which==2)?pw2:(which==3)?pw3:outp;
  short* dst = (which < 4) ? (wpreT + which*262144) : woutT;
  int bi = blockIdx.x >> 3, bj = blockIdx.x & 7;
  int r0 = bi*64, c0 = bj*64;
  int t = threadIdx.x;
  int row = t >> 2, cg = t & 3;
  const float4* s4 = (const float4*)(src + (r0+row)*512 + c0 + cg*16);
  #pragma unroll
  for (int i=0;i<4;i++){
    float4 v = s4[i];
    tile[row][cg*16 + i*4 + 0] = v.x;
    tile[row][cg*16 + i*4 + 1] = v.y;
    tile[row][cg*16 + i*4 + 2] = v.z;
    tile[row][cg*16 + i*4 + 3] = v.w;
  }
  __syncthreads();
  int oc = t >> 2;
  short tmp[16];
  #pragma unroll
  for (int i=0;i<16;i++) tmp[i] = f2bf(tile[cg*16 + i][oc]);
  short* dp = dst + (size_t)(c0+oc)*512 + r0 + cg*16;
  *(bf16x8*)(dp)     = *(bf16x8*)tmp;
  *(bf16x8*)(dp + 8) = *((bf16x8*)tmp + 1);
}

__global__ __launch_bounds__(256) void k_tok(const float* __restrict__ t, short* __restrict__ o){
  int i = (blockIdx.x*256 + threadIdx.x) * 4;
  float4 v = *(const float4*)(t + i);
  uint32_t p0 = (uint32_t)(uint16_t)f2bf(v.x) | ((uint32_t)(uint16_t)f2bf(v.y) << 16);
  uint32_t p1 = (uint32_t)(uint16_t)f2bf(v.z) | ((uint32_t)(uint16_t)f2bf(v.w) << 16);
  uint2 p; p.x = p0; p.y = p1;
  *(uint2*)(o + i) = p;
}

// ---------- prep: b_xz (blocks 0-7) + gains/biasc (block 8) ----------
__global__ __launch_bounds__(256) void k_bxz_gains(const float* __restrict__ in_proj,
    const float* __restrict__ b0, const float* __restrict__ b1,
    const float* __restrict__ b2, const float* __restrict__ b3,
    const float* __restrict__ gl,
    const float* __restrict__ pb0, const float* __restrict__ pb1,
    const float* __restrict__ pb2, const float* __restrict__ pb3,
    float* __restrict__ bxz, float* __restrict__ gains, float* __restrict__ biasc)
{
  if (blockIdx.x < 8){
    int idx = blockIdx.x*256 + threadIdx.x;   // 0..2047
    int g = idx >> 9, i = idx & 511;
    const float* bb = (g==0)?b0:(g==1)?b1:(g==2)?b2:b3;
    float s = 0.f;
    for (int t=0;t<512;t++) s += in_proj[i*512+t]*bb[t];
    bxz[idx] = s;
  } else {
    float m = fmaxf(fmaxf(gl[0], gl[1]), fmaxf(gl[2], gl[3]));
    float e0 = expf(gl[0]-m), e1 = expf(gl[1]-m), e2 = expf(gl[2]-m), e3 = expf(gl[3]-m);
    float s = e0+e1+e2+e3;
    float g0 = e0/s, g1 = e1/s, g2 = e2/s, g3 = e3/s;
    int t = threadIdx.x;
    if (t == 0){ gains[0]=g0; gains[1]=g1; gains[2]=g2; gains[3]=g3; }
    biasc[t]     = g0*pb0[t]     + g1*pb1[t]     + g2*pb2[t]     + g3*pb3[t];
    biasc[t+256] = g0*pb0[t+256] + g1*pb1[t+256] + g2*pb2[t+256] + g3*pb3[t+256];
  }
}

// ---------- register-GEMM core for the tiny weight-fuse GEMMs ----------
__device__ __forceinline__ void mfma_2x4_k(const short* a0, const short* a1,
    const short* b0, const short* b1, const short* b2, const short* b3,
    int K, f32x4 acc[2][4])
{
  for (int k0 = 0; k0 < K; k0 += 32){
    bf16x8 av0 = *(const bf16x8*)(a0 + k0);
    bf16x8 av1 = *(const bf16x8*)(a1 + k0);
    bf16x8 bv0 = *(const bf16x8*)(b0 + k0);
    bf16x8 bv1 = *(const bf16x8*)(b1 + k0);
    bf16x8 bv2 = *(const bf16x8*)(b2 + k0);
    bf16x8 bv3 = *(const bf16x8*)(b3 + k0);
    acc[0][0] = __builtin_amdgcn_mfma_f32_16x16x32_bf16(av0, bv0, acc[0][0],0,0,0);
    acc[0][1] = __builtin_amdgcn_mfma_f32_16x16x32_bf16(av0, bv1, acc[0][1],0,0,0);
    acc[0][2] = __builtin_amdgcn_mfma_f32_16x16x32_bf16(av0, bv2, acc[0][2],0,0,0);
    acc[0][3] = __builtin_amdgcn_mfma_f32_16x16x32_bf16(av0, bv3, acc[0][3],0,0,0);
    acc[1][0] = __builtin_amdgcn_mfma_f32_16x16x32_bf16(av1, bv0, acc[1][0],0,0,0);
    acc[1][1] = __builtin_amdgcn_mfma_f32_16x16x32_bf16(av1, bv1, acc[1][1],0,0,0);
    acc[1][2] = __builtin_amdgcn_mfma_f32_16x16x32_bf16(av1, bv2, acc[1][2],0,0,0);
    acc[1][3] = __builtin_amdgcn_mfma_f32_16x16x32_bf16(av1, bv3, acc[1][3],0,0,0);
  }
}

// ---------- merged weight-fuse: z<4 -> W_xz[g]; z>=4 -> Wog[g] ----------
__global__ __launch_bounds__(256) void k_wfuse(const short* __restrict__ inp_bf,
    const short* __restrict__ wpreT, const short* __restrict__ postw_bf,
    const short* __restrict__ woutT, const float* __restrict__ gains,
    short* __restrict__ wxz, short* __restrict__ wogc)
{
  int z = blockIdx.z; int g = z & 3, which = z >> 2;
  int bn = blockIdx.x * 64, bm = blockIdx.y * 128;
  int lane = threadIdx.x & 63, wave = threadIdx.x >> 6;
  int mr = lane & 15, qk = (lane >> 4) * 8, quad = lane >> 4;
  const short* Am = which ? (postw_bf + g*262144) : inp_bf;
  const short* Bm = which ? woutT : (wpreT + g*262144);
  const short* a0 = Am + (bm + wave*32 + mr)*512 + qk;
  const short* a1 = a0 + 16*512;
  const short* b0 = Bm + (bn +  0 + mr)*512 + qk;
  const short* b1 = Bm + (bn + 16 + mr)*512 + qk;
  const short* b2 = Bm + (bn + 32 + mr)*512 + qk;
  const short* b3 = Bm + (bn + 48 + mr)*512 + qk;
  f32x4 acc[2][4] = {};
  mfma_2x4_k(a0, a1, b0, b1, b2, b3, 512, acc);
  float gain = which ? gains[g] : 1.f;
  #pragma unroll
  for (int s=0;s<2;s++)
    #pragma unroll
    for (int t=0;t<4;t++)
      #pragma unroll
      for (int r=0;r<4;r++){
        int row = bm + wave*32 + s*16 + quad*4 + r;
        int col = bn + t*16 + mr;
        if (which) wogc[row*2048 + g*512 + col] = f2bf(gain * acc[s][t][r]);
        else       wxz[g*262144 + row*512 + col] = f2bf(acc[s][t][r]);
      }
}

// ---------- GEMM1: 256x256 tile, BK=32, K=512 (NT=16), grid 784, XCD-swizzled ----------
// xz[(g*512+b)*49+l][ch] = tok[b][perm_g(l)][:] @ W_xz[g]^T + b_xz[g]
__global__ __launch_bounds__(512) void k_gemm1(const short* __restrict__ tok,
    const short* __restrict__ wxz, const float* __restrict__ bxz, short* __restrict__ xz)
{
  __shared__ __align__(16) short S[32768];    // 64 KB: 2 buf x (A 16KB | B 16KB)
  int bid = blockIdx.x;                       // 784 = 8 * 98, bijective XCD swizzle
  int swz = (bid & 7) * 98 + (bid >> 3);
  int g = swz / 196, rem = swz - g*196;
  int bm = (rem >> 1) * 256, bn = (rem & 1) * 256;
  int tid = threadIdx.x, lane = tid & 63, w = tid >> 6;

  int rl = lane >> 2;                                 // row within 16-row unit
  int gch = ((lane & 3) ^ ((lane >> 3) & 3)) * 8;     // pre-swizzled global chunk
  const short* aU[2];
  #pragma unroll
  for (int j = 0; j < 2; ++j){
    int grow = bm + w*32 + j*16 + rl;
    int b = grow / 49, l49 = grow - b*49;
    int sl = perm_idx(g, l49);
    aU[j] = tok + ((size_t)(b*49 + sl))*512 + gch;
  }
  const short* bU0 = wxz + (size_t)g*262144 + (size_t)(bn + w*32      + rl)*512 + gch;
  const short* bU1 = wxz + (size_t)g*262144 + (size_t)(bn + w*32 + 16 + rl)*512 + gch;

  f32x4 acc[8][4] = {};
  kcore256<16>(aU[0], aU[1], bU0, bU1, S, w, lane, acc);

  int wr = w >> 2, wc = w & 3, mr = lane & 15, quad = lane >> 4;
  #pragma unroll
  for (int mf = 0; mf < 8; ++mf)
    #pragma unroll
    for (int rr = 0; rr < 4; ++rr){
      int row = bm + wr*128 + mf*16 + quad*4 + rr;
      int b = row / 49, l = row - b*49;
      size_t orow = ((size_t)(g*512 + b)*49 + l)*512;
      #pragma unroll
      for (int nf = 0; nf < 4; ++nf){
        int col = bn + wc*64 + nf*16 + mr;
        xz[orow + col] = f2bf(acc[mf][nf][rr] + bxz[g*512 + col]);
      }
    }
}

// ---------- k_conv: depthwise conv3 + SiLU, fully parallel ----------
__global__ __launch_bounds__(256) void k_conv(const short* __restrict__ xz,
    const float* __restrict__ cxw, const float* __restrict__ cxb,
    const float* __restrict__ czw, const float* __restrict__ czb,
    short* __restrict__ ycat)
{
  int t = threadIdx.x;
  int oct = t & 63, lstart = t >> 6;
  int ch0 = oct * 8;
  bool isx = ch0 < 256;
  int cc0 = isx ? ch0 : ch0 - 256;
  const float* wsrc = isx ? cxw : czw;
  const float* bsrc = isx ? cxb : czb;
  float w0[8], w1[8], w2[8], bb[8];
  #pragma unroll
  for (int e=0;e<8;e++){
    w0[e] = wsrc[(cc0+e)*3]; w1[e] = wsrc[(cc0+e)*3+1]; w2[e] = wsrc[(cc0+e)*3+2];
    bb[e] = bsrc[cc0+e];
  }
  int gb = blockIdx.x; int g = gb >> 9, b = gb & 511;
  const short* src = xz + (size_t)gb*25088 + ch0;
  short* dst = ycat + (size_t)(b*49)*2048 + g*512 + ch0;
  for (int l = lstart; l < 49; l += 4){
    bf16x8 vm = {}, vp = {};
    bf16x8 v0 = *(const bf16x8*)(src + l*512);
    if (l > 0)  vm = *(const bf16x8*)(src + (l-1)*512);
    if (l < 48) vp = *(const bf16x8*)(src + (l+1)*512);
    short ov[8];
    #pragma unroll
    for (int e=0;e<8;e++){
      float x = w0[e]*bf2f(vm[e]) + w1[e]*bf2f(v0[e]) + w2[e]*bf2f(vp[e]) + bb[e];
      ov[e] = f2bf(x / (1.f + __expf(-x)));
    }
    *(bf16x8*)(dst + l*2048) = *(bf16x8*)ov;
  }
}

// ---------- k_xproj: x_proj GEMM + LN + dt GEMM + softplus ----------
__global__ __launch_bounds__(256) void k_xproj(const short* __restrict__ ycat,
    const short* __restrict__ xpw_bf, const float* __restrict__ lnw, const float* __restrict__ lnb,
    const short* __restrict__ dtw_bf, const float* __restrict__ dtb,
    short* __restrict__ dtln, float* __restrict__ bc)
{
  // LDS: xd f32 [128][52] = 26624 B ; xln_bf bf16 [128][40] = 10240 B
  __shared__ __align__(16) char smem[36864];
  float* xd = (float*)smem;
  short* xln = (short*)(smem + 26624);

  int bm = blockIdx.x * 128;
  int g = bm / 25088;                   // uniform per block (128 | 25088)
  int tid = threadIdx.x, lane = tid & 63, w = tid >> 6;
  int mr = lane & 15, quad = lane >> 4, qk = quad * 8;

  // ---- phase 1: x_dbl = u @ xpw^T  (tile 128x48, K=256) ----
  {
    const short* ap[2];
    #pragma unroll
    for (int s=0;s<2;s++)
      ap[s] = ycat + (size_t)(bm - g*25088 + w*32 + s*16 + mr)*2048 + g*512 + qk;
    f32x4 acc[2][3] = {};
    #pragma unroll
    for (int k0 = 0; k0 < 256; k0 += 32){
      bf16x8 av[2];
      #pragma unroll
      for (int s=0;s<2;s++) av[s] = *(const bf16x8*)(ap[s] + k0);
      #pragma unroll
      for (int t=0;t<3;t++){
        bf16x8 bv = *(const bf16x8*)(xpw_bf + (t*16 + mr)*256 + qk + k0);
        #pragma unroll
        for (int s=0;s<2;s++)
          acc[s][t] = __builtin_amdgcn_mfma_f32_16x16x32_bf16(av[s], bv, acc[s][t],0,0,0);
      }
    }
    #pragma unroll
    for (int s=0;s<2;s++)
      #pragma unroll
      for (int t=0;t<3;t++)
        #pragma unroll
        for (int r=0;r<4;r++)
          xd[(w*32 + s*16 + quad*4 + r)*52 + t*16 + mr] = acc[s][t][r];
  }
  __syncthreads();

  // ---- phase 2: LN per row (threads 0..127), write dt-cols to xln (bf16) + B/C to global ----
  if (tid < 128){
    f32x4* xr4 = (f32x4*)(xd + tid*52);
    f32x4 s = xr4[0];
    #pragma unroll
    for (int i=1;i<12;i++) s += xr4[i];
    float m = (s[0]+s[1]+s[2]+s[3]) * (1.f/48.f);
    f32x4 vs = {};
    #pragma unroll
    for (int i=0;i<12;i++){ f32x4 d = xr4[i] - m; vs += d*d; }
    float var = (vs[0]+vs[1]+vs[2]+vs[3]) * (1.f/48.f);
    float rstd = rsqrtf(var + 1e-5f);
    const f32x4* g4 = (const f32x4*)lnw;
    const f32x4* b4 = (const f32x4*)lnb;
    uint32_t* xlr = (uint32_t*)(xln + tid*40);
    #pragma unroll
    for (int i=0;i<8;i++){       // cols 0..31 -> xln bf16
      f32x4 v = (xr4[i] - m) * rstd * g4[i] + b4[i];
      xlr[2*i]   = (uint32_t)(uint16_t)f2bf(v[0]) | ((uint32_t)(uint16_t)f2bf(v[1]) << 16);
      xlr[2*i+1] = (uint32_t)(uint16_t)f2bf(v[2]) | ((uint32_t)(uint16_t)f2bf(v[3]) << 16);
    }
    f32x4* bco = (f32x4*)(bc + (size_t)(bm + tid)*16);
    #pragma unroll
    for (int i=8;i<12;i++)       // cols 32..47 -> bc f32
      bco[i-8] = (xr4[i] - m) * rstd * g4[i] + b4[i];
  }
  __syncthreads();

  // ---- phase 3: dt = xln[:,0:32] @ dtw^T (K=32, N=256) + bias + softplus -> dtln ----
  // softplus via hardware exp2/log2 path; for x>15 select x (err << bf16 ulp).
  {
    bf16x8 a[2];
    #pragma unroll
    for (int s=0;s<2;s++)
      a[s] = *(const bf16x8*)(xln + (w*32 + s*16 + mr)*40 + qk);
    #pragma unroll 4
    for (int nt=0; nt<16; nt++){
      int col = nt*16 + mr;
      bf16x8 bv = *(const bf16x8*)(dtw_bf + col*32 + qk);
      float dtbv = dtb[col];
      #pragma unroll
      for (int s=0;s<2;s++){
        f32x4 acc = {};
        acc = __builtin_amdgcn_mfma_f32_16x16x32_bf16(a[s], bv, acc,0,0,0);
        #pragma unroll
        for (int r=0;r<4;r++){
          int grow = bm + w*32 + s*16 + quad*4 + r;
          float dtv = acc[r] + dtbv;
          float e  = __expf(dtv);
          float sp = __logf(1.f + e);
          float delta = (dtv > 15.f) ? dtv : sp;
          dtln[(size_t)grow*256 + col] = f2bf(delta);
        }
      }
    }
  }
}

// ---------- k_scan: selective scan, one block per gb, u->y in place ----------
__global__ __launch_bounds__(256) void k_scan(short* __restrict__ ycat,
    const short* __restrict__ dtln, const float* __restrict__ bc,
    const float* __restrict__ Alog, const float* __restrict__ Dp)
{
  __shared__ __align__(16) float bcs[784];   // [49][16]
  int gb = blockIdx.x; int g = gb >> 9, b = gb & 511;
  int d = threadIdx.x;
  if (d < 196) ((f32x4*)bcs)[d] = ((const f32x4*)(bc + (size_t)gb*784))[d];
  __syncthreads();

  float A[8], h[8];
  {
    f32x4 a0 = *(const f32x4*)(Alog + d*8);
    f32x4 a1 = *(const f32x4*)(Alog + d*8 + 4);
    #pragma unroll
    for (int n=0;n<4;n++){ A[n] = -__expf(a0[n]); A[n+4] = -__expf(a1[n]); h[n]=0.f; h[n+4]=0.f; }
  }
  float Dpar = Dp[d];

  const short* dptr = dtln + (size_t)gb*49*256 + d;
  short* uptr = ycat + (size_t)(b*49)*2048 + g*512 + d;

  float dn = bf2f(dptr[0]);
  float un = bf2f(uptr[0]);
  for (int l=0;l<49;l++){
    float delta = dn, u = un;
    if (l < 48){ dn = bf2f(dptr[(l+1)*256]); un = bf2f(uptr[(l+1)*2048]); }
    const f32x4* bcr = (const f32x4*)(bcs + l*16);
    f32x4 B0 = bcr[0], B1 = bcr[1], C0 = bcr[2], C1 = bcr[3];
    float du = delta * u;
    float y = 0.f;
    #pragma unroll
    for (int n=0;n<4;n++){
      h[n] = h[n]*__expf(delta*A[n]) + du*B0[n];
      y += h[n]*C0[n];
    }
    #pragma unroll
    for (int n=0;n<4;n++){
      h[n+4] = h[n+4]*__expf(delta*A[n+4]) + du*B1[n];
      y += h[n+4]*C1[n];
    }
    uptr[l*2048] = f2bf(y + Dpar*u);
  }
}

// ---------- final GEMM: 256x256 tile, BK=32, K=2048 (NT=64), grid 196 ----------
__global__ __launch_bounds__(512) void k_gemmF(const short* __restrict__ ycat,
    const short* __restrict__ wogc, const float* __restrict__ biasc,
    float* __restrict__ out)
{
  __shared__ __align__(16) short S[32768];    // 64 KB: 2 buf x (A 16KB | B 16KB)
  int bid = blockIdx.x;                       // 196 = 98 bm x 2 bn (single round)
  int bm = (bid >> 1) * 256, bn = (bid & 1) * 256;
  int tid = threadIdx.x, lane = tid & 63, w = tid >> 6;

  int rl = lane >> 2;                                 // row within 16-row unit
  int gch = ((lane & 3) ^ ((lane >> 3) & 3)) * 8;     // pre-swizzled global chunk
  const short* aU0 = ycat + (size_t)(bm + w*32      + rl)*2048 + gch;
  const short* aU1 = ycat + (size_t)(bm + w*32 + 16 + rl)*2048 + gch;
  const short* bU0 = wogc + (size_t)(bn + w*32      + rl)*2048 + gch;
  const short* bU1 = wogc + (size_t)(bn + w*32 + 16 + rl)*2048 + gch;

  f32x4 acc[8][4] = {};
  kcore256<64>(aU0, aU1, bU0, bU1, S, w, lane, acc);

  int wr = w >> 2, wc = w & 3, mr = lane & 15, quad = lane >> 4;
  #pragma unroll
  for (int mf = 0; mf < 8; ++mf)
    #pragma unroll
    for (int rr = 0; rr < 4; ++rr){
      int row = bm + wr*128 + mf*16 + quad*4 + rr;
      float* orow = out + (size_t)row*512;
      #pragma unroll
      for (int nf = 0; nf < 4; ++nf){
        int col = bn + wc*64 + nf*16 + mr;
        orow[col] = acc[mf][nf][rr] + biasc[col];
      }
    }
}

// ---------- launch ----------
extern "C" void kernel_launch(void* const* d_in, const int* in_sizes, int n_in,
                              void* d_out, int out_size, void* d_ws, size_t ws_size,
                              hipStream_t stream)
{
  const float* tokens    = (const float*)d_in[0];
  const float* pre_w[4]  = {(const float*)d_in[1], (const float*)d_in[3], (const float*)d_in[5], (const float*)d_in[7]};
  const float* pre_b[4]  = {(const float*)d_in[2], (const float*)d_in[4], (const float*)d_in[6], (const float*)d_in[8]};
  const float* post_w[4] = {(const float*)d_in[9], (const float*)d_in[11], (const float*)d_in[13], (const float*)d_in[15]};
  const float* post_b[4] = {(const float*)d_in[10], (const float*)d_in[12], (const float*)d_in[14], (const float*)d_in[16]};
  const float* in_proj   = (const float*)d_in[17];
  const float* conv_x_w  = (const float*)d_in[18];
  const float* conv_x_b  = (const float*)d_in[19];
  const float* conv_z_w  = (const float*)d_in[20];
  const float* conv_z_b  = (const float*)d_in[21];
  const float* x_proj_w  = (const float*)d_in[22];
  const float* ln_w      = (const float*)d_in[23];
  const float* ln_b      = (const float*)d_in[24];
  const float* dt_proj_w = (const float*)d_in[25];
  const float* dt_proj_b = (const float*)d_in[26];
  const float* A_log     = (const float*)d_in[27];
  const float* D_param   = (const float*)d_in[28];
  const float* out_proj  = (const float*)d_in[29];
  const float* gate_log  = (const float*)d_in[30];

  char* ws = (char*)d_ws;
  size_t o = 0;
  short* tok_bf   = (short*)(ws + o); o += 25690112;   // 12845056 bf16
  short* wpreT    = (short*)(ws + o); o += 2097152;    // 4x 512x512 bf16 (transposed)
  short* inp_bf   = (short*)(ws + o); o += 524288;
  short* postw_bf = (short*)(ws + o); o += 2097152;
  short* woutT    = (short*)(ws + o); o += 524288;
  short* wogc     = (short*)(ws + o); o += 2097152;    // 512 x 2048 bf16
  short* wxz      = (short*)(ws + o); o += 2097152;    // 4x 512x512 bf16
  short* xpw_bf   = (short*)(ws + o); o += 24576;      // 48x256 bf16
  short* dtw_bf   = (short*)(ws + o); o += 16384;      // 256x32 bf16
  float* bxz      = (float*)(ws + o); o += 8192;
  float* gains    = (float*)(ws + o); o += 64;
  float* biasc    = (float*)(ws + o); o += 2048;
  size_t xz_off = o;
  short* xz       = (short*)(ws + o); o += 102760448;  // 2048*49*512 bf16
  short* ycat     = (short*)(ws + o); o += 102760448;  // 25088 x 2048 bf16
  // dtln (51.4 MB) + bc (6.4 MB) alias the xz region: xz is dead after k_conv.
  short* dtln     = (short*)(ws + xz_off);
  float* bc       = (float*)(ws + xz_off + 51380224);

  k_conv_all<<<1300, 256, 0, stream>>>(in_proj,
      post_w[0], post_w[1], post_w[2], post_w[3],
      x_proj_w, dt_proj_w, inp_bf, postw_bf, xpw_bf, dtw_bf);
  k_transp<<<dim3(64,5), 256, 0, stream>>>(pre_w[0], pre_w[1], pre_w[2], pre_w[3],
      out_proj, wpreT, woutT);
  k_tok<<<12544, 256, 0, stream>>>(tokens, tok_bf);
  k_bxz_gains<<<9, 256, 0, stream>>>(in_proj, pre_b[0], pre_b[1], pre_b[2], pre_b[3],
      gate_log, post_b[0], post_b[1], post_b[2], post_b[3], bxz, gains, biasc);
  k_wfuse<<<dim3(8,4,8), 256, 0, stream>>>(inp_bf, wpreT, postw_bf, woutT, gains, wxz, wogc);
  k_gemm1<<<dim3(784), 512, 0, stream>>>(tok_bf, wxz, bxz, xz);
  k_conv<<<2048, 256, 0, stream>>>(xz, conv_x_w, conv_x_b, conv_z_w, conv_z_b, ycat);
  k_xproj<<<784, 256, 0, stream>>>(ycat, xpw_bf, ln_w, ln_b, dtw_bf, dt_proj_b, dtln, bc);
  k_scan<<<2048, 256, 0, stream>>>(ycat, dtln, bc, A_log, D_param);
  k_gemmF<<<dim3(196), 512, 0, stream>>>(ycat, wogc, biasc, (float*)d_out);
}

// Round 6
// 482.892 us; speedup vs baseline: 1.0914x; 1.0626x over previous
//
#include <hip/hip_runtime.h>
#include <stdint.h>

// ---------- types ----------
typedef __attribute__((ext_vector_type(8))) short bf16x8;   // 8 bf16 in 4 VGPRs
typedef __attribute__((ext_vector_type(4))) float f32x4;

__device__ __forceinline__ float bf2f(short u){
  union { float f; uint32_t i; } v; v.i = ((uint32_t)(uint16_t)u) << 16; return v.f;
}
__device__ __forceinline__ short f2bf(float x){
  union { float f; uint32_t i; } v; v.f = x;
  uint32_t r = v.i + 0x7FFFu + ((v.i >> 16) & 1u);   // RNE
  return (short)(r >> 16);
}

// async global->LDS, 16B per lane; LDS dest = wave-uniform base + lane*16
__device__ __forceinline__ void gl_lds16(const short* g, short* l){
  __builtin_amdgcn_global_load_lds(
      (__attribute__((address_space(1))) void*)(short*)g,
      (__attribute__((address_space(3))) void*)l, 16, 0, 0);
}

// ---------- permutation tables (WIN=7, compile-time) ----------
__device__ const int d_DIAG[49] = {0,1,7,2,8,14,3,9,15,21,4,10,16,22,28,5,11,17,23,29,35,
  6,12,18,24,30,36,42,13,19,25,31,37,43,20,26,32,38,44,27,33,39,45,34,40,46,41,47,48};
__device__ const int d_ANTI[49] = {6,5,13,4,12,20,3,11,19,27,2,10,18,26,34,1,9,17,25,33,41,
  0,8,16,24,32,40,48,7,15,23,31,39,47,14,22,30,38,46,21,29,37,45,28,36,44,35,43,42};

__device__ __forceinline__ int perm_idx(int g, int l){
  if (g == 0) return l;
  if (g == 1) return (l % 7) * 7 + l / 7;  // V_IDX
  if (g == 2) return d_DIAG[l];
  return d_ANTI[l];
}

// ---------- 256x256 K-loop core (kept for gemmF): BK=32, 8 waves (2M x 4N) ----------
template<int NT>
__device__ __forceinline__ void kcore256(
    const short* aU0, const short* aU1, const short* bU0, const short* bU1,
    short* S, int w, int lane, f32x4 acc[8][4])
{
  int wr = w >> 2, wc = w & 3;
  int mr = lane & 15, quad = lane >> 4;
  int sw = (quad ^ ((mr >> 1) & 3)) * 8;     // swizzled chunk offset (shorts)
  auto STAGE = [&](int u, int t){
    short* base = S + (t & 1) * 16384;
    if      (u == 0) gl_lds16(aU0 + t*32, base + (w*32)*32);
    else if (u == 1) gl_lds16(aU1 + t*32, base + (w*32 + 16)*32);
    else if (u == 2) gl_lds16(bU0 + t*32, base + 8192 + (w*32)*32);
    else             gl_lds16(bU1 + t*32, base + 8192 + (w*32 + 16)*32);
  };
  STAGE(0,0); STAGE(1,0); STAGE(2,0); STAGE(3,0);
  if (NT > 1){ STAGE(0,1); STAGE(1,1); }
  asm volatile("s_waitcnt vmcnt(2)" ::: "memory");
  __builtin_amdgcn_s_barrier();
  for (int t = 0; t < NT; ++t){
    const short* Ab = S + (t & 1) * 16384;
    const short* Bb = Ab + 8192;
    bf16x8 bfr[4];
    #pragma unroll
    for (int nf = 0; nf < 4; ++nf)
      bfr[nf] = *(const bf16x8*)(Bb + (wc*64 + nf*16 + mr)*32 + sw);
    #pragma unroll
    for (int ph = 0; ph < 4; ++ph){
      bf16x8 af[2];
      #pragma unroll
      for (int mi = 0; mi < 2; ++mi)
        af[mi] = *(const bf16x8*)(Ab + (wr*128 + (ph*2+mi)*16 + mr)*32 + sw);
      if (ph < 2 && t+1 < NT) STAGE(2+ph, t+1);   // B-units of t+1 -> buf (t+1)&1
      #pragma unroll
      for (int mi = 0; mi < 2; ++mi)
        #pragma unroll
        for (int nf = 0; nf < 4; ++nf)
          acc[ph*2+mi][nf] = __builtin_amdgcn_mfma_f32_16x16x32_bf16(af[mi], bfr[nf], acc[ph*2+mi][nf],0,0,0);
    }
    __builtin_amdgcn_s_barrier();            // all waves done reading buf t&1
    if (t+2 < NT){
      STAGE(0, t+2); STAGE(1, t+2);          // A-units of t+2 -> just-freed buf
      asm volatile("s_waitcnt vmcnt(2)" ::: "memory");   // all of t+1 landed
    } else if (t+1 < NT){
      asm volatile("s_waitcnt vmcnt(0)" ::: "memory");   // tail drain (once)
    }
    __builtin_amdgcn_s_barrier();            // all waves' t+1 loads visible
  }
}

// ---------- 256x128 K-loop core (gemm1): BK=32, 8 waves (4M x 2N), 48KB LDS ----------
// LDS buffer stride 12288 shorts (24KB): A [256r][32] at +0, B [128r][32] at +8192.
// Per wave per tile: 3 stage units (A rows w*32..+31 x2, B rows w*16..+15 x1).
// Boundary: barrier1; stage A(t+2)x2; vmcnt(2) (newest 2 = A(t+2) in flight,
// A(t+1)+B(t+1) landed); barrier2. In-loop: stage B(t+1) (dest buf not read).
template<int NT>
__device__ __forceinline__ void kcore256x128(
    const short* aU0, const short* aU1, const short* bU,
    short* S, int w, int lane, f32x4 acc[4][4])
{
  int wr = w >> 1, wc = w & 1;
  int mr = lane & 15, quad = lane >> 4;
  int sw = (quad ^ ((mr >> 1) & 3)) * 8;     // swizzled chunk offset (shorts)
  auto STAGE_A = [&](int t){
    short* base = S + (t & 1) * 12288;
    gl_lds16(aU0 + t*32, base + (w*32)*32);
    gl_lds16(aU1 + t*32, base + (w*32 + 16)*32);
  };
  auto STAGE_B = [&](int t){
    short* base = S + (t & 1) * 12288;
    gl_lds16(bU + t*32, base + 8192 + (w*16)*32);
  };
  STAGE_A(0); STAGE_B(0);
  if (NT > 1) STAGE_A(1);
  asm volatile("s_waitcnt vmcnt(2)" ::: "memory");   // tile 0's 3 loads done
  __builtin_amdgcn_s_barrier();
  for (int t = 0; t < NT; ++t){
    const short* Ab = S + (t & 1) * 12288;
    const short* Bb = Ab + 8192;
    bf16x8 bfr[4];
    #pragma unroll
    for (int nf = 0; nf < 4; ++nf)
      bfr[nf] = *(const bf16x8*)(Bb + (wc*64 + nf*16 + mr)*32 + sw);
    #pragma unroll
    for (int ph = 0; ph < 4; ++ph){
      bf16x8 af = *(const bf16x8*)(Ab + (wr*64 + ph*16 + mr)*32 + sw);
      if (ph == 1 && t+1 < NT) STAGE_B(t+1);       // B of t+1 -> buf (t+1)&1
      #pragma unroll
      for (int nf = 0; nf < 4; ++nf)
        acc[ph][nf] = __builtin_amdgcn_mfma_f32_16x16x32_bf16(af, bfr[nf], acc[ph][nf],0,0,0);
    }
    __builtin_amdgcn_s_barrier();            // all waves done reading buf t&1
    if (t+2 < NT){
      STAGE_A(t+2);                          // A of t+2 -> just-freed buf
      asm volatile("s_waitcnt vmcnt(2)" ::: "memory");   // A(t+1)+B(t+1) landed
    } else if (t+1 < NT){
      asm volatile("s_waitcnt vmcnt(0)" ::: "memory");   // tail drain (once)
    }
    __builtin_amdgcn_s_barrier();            // all waves' t+1 loads visible
  }
}

// ---------- prep: plain f32->bf16 converts (in_proj, post x4, x_proj_w, dt_proj_w) ----------
__global__ __launch_bounds__(256) void k_conv_all(
    const float* __restrict__ in_proj,
    const float* __restrict__ pw0, const float* __restrict__ pw1,
    const float* __restrict__ pw2, const float* __restrict__ pw3,
    const float* __restrict__ xpw, const float* __restrict__ dtw,
    short* __restrict__ inp_bf, short* __restrict__ postw_bf,
    short* __restrict__ xpw_bf, short* __restrict__ dtw_bf)
{
  int q = blockIdx.x*256 + threadIdx.x;   // quad index, total 332800
  const float* src; short* dst; int off;
  if (q < 65536){ src = in_proj; dst = inp_bf; off = q; }
  else if (q < 65536 + 262144){
    int r = q - 65536; int g = r >> 16; int loc = r & 65535;
    src = (g==0)?pw0:(g==1)?pw1:(g==2)?pw2:pw3;
    dst = postw_bf + g*262144; off = loc;
  }
  else if (q < 65536 + 262144 + 3072){ src = xpw; dst = xpw_bf; off = q - (65536+262144); }
  else { src = dtw; dst = dtw_bf; off = q - (65536+262144+3072); }
  float4 v = *(const float4*)(src + off*4);
  uint32_t p0 = (uint32_t)(uint16_t)f2bf(v.x) | ((uint32_t)(uint16_t)f2bf(v.y) << 16);
  uint32_t p1 = (uint32_t)(uint16_t)f2bf(v.z) | ((uint32_t)(uint16_t)f2bf(v.w) << 16);
  uint2 p; p.x = p0; p.y = p1;
  *(uint2*)(dst + off*4) = p;
}

// ---------- prep: LDS-tiled transpose+convert (pre_w x4 -> wpreT, out_proj -> woutT) ----------
__global__ __launch_bounds__(256) void k_transp(
    const float* __restrict__ pw0, const float* __restrict__ pw1,
    const float* __restrict__ pw2, const float* __restrict__ pw3,
    const float* __restrict__ outp,
    short* __restrict__ wpreT, short* __restrict__ woutT)
{
  __shared__ float tile[64][65];
  int which = blockIdx.y;
  const float* src = (which==0)?pw0:(which==1)?pw1:(which==2)?pw2:(which==3)?pw3:outp;
  short* dst = (which < 4) ? (wpreT + which*262144) : woutT;
  int bi = blockIdx.x >> 3, bj = blockIdx.x & 7;
  int r0 = bi*64, c0 = bj*64;
  int t = threadIdx.x;
  int row = t >> 2, cg = t & 3;
  const float4* s4 = (const float4*)(src + (r0+row)*512 + c0 + cg*16);
  #pragma unroll
  for (int i=0;i<4;i++){
    float4 v = s4[i];
    tile[row][cg*16 + i*4 + 0] = v.x;
    tile[row][cg*16 + i*4 + 1] = v.y;
    tile[row][cg*16 + i*4 + 2] = v.z;
    tile[row][cg*16 + i*4 + 3] = v.w;
  }
  __syncthreads();
  int oc = t >> 2;
  short tmp[16];
  #pragma unroll
  for (int i=0;i<16;i++) tmp[i] = f2bf(tile[cg*16 + i][oc]);
  short* dp = dst + (size_t)(c0+oc)*512 + r0 + cg*16;
  *(bf16x8*)(dp)     = *(bf16x8*)tmp;
  *(bf16x8*)(dp + 8) = *((bf16x8*)tmp + 1);
}

__global__ __launch_bounds__(256) void k_tok(const float* __restrict__ t, short* __restrict__ o){
  int i = (blockIdx.x*256 + threadIdx.x) * 4;
  float4 v = *(const float4*)(t + i);
  uint32_t p0 = (uint32_t)(uint16_t)f2bf(v.x) | ((uint32_t)(uint16_t)f2bf(v.y) << 16);
  uint32_t p1 = (uint32_t)(uint16_t)f2bf(v.z) | ((uint32_t)(uint16_t)f2bf(v.w) << 16);
  uint2 p; p.x = p0; p.y = p1;
  *(uint2*)(o + i) = p;
}

// ---------- prep: b_xz (blocks 0-7) + gains/biasc (block 8) ----------
__global__ __launch_bounds__(256) void k_bxz_gains(const float* __restrict__ in_proj,
    const float* __restrict__ b0, const float* __restrict__ b1,
    const float* __restrict__ b2, const float* __restrict__ b3,
    const float* __restrict__ gl,
    const float* __restrict__ pb0, const float* __restrict__ pb1,
    const float* __restrict__ pb2, const float* __restrict__ pb3,
    float* __restrict__ bxz, float* __restrict__ gains, float* __restrict__ biasc)
{
  if (blockIdx.x < 8){
    int idx = blockIdx.x*256 + threadIdx.x;   // 0..2047
    int g = idx >> 9, i = idx & 511;
    const float* bb = (g==0)?b0:(g==1)?b1:(g==2)?b2:b3;
    float s = 0.f;
    for (int t=0;t<512;t++) s += in_proj[i*512+t]*bb[t];
    bxz[idx] = s;
  } else {
    float m = fmaxf(fmaxf(gl[0], gl[1]), fmaxf(gl[2], gl[3]));
    float e0 = expf(gl[0]-m), e1 = expf(gl[1]-m), e2 = expf(gl[2]-m), e3 = expf(gl[3]-m);
    float s = e0+e1+e2+e3;
    float g0 = e0/s, g1 = e1/s, g2 = e2/s, g3 = e3/s;
    int t = threadIdx.x;
    if (t == 0){ gains[0]=g0; gains[1]=g1; gains[2]=g2; gains[3]=g3; }
    biasc[t]     = g0*pb0[t]     + g1*pb1[t]     + g2*pb2[t]     + g3*pb3[t];
    biasc[t+256] = g0*pb0[t+256] + g1*pb1[t+256] + g2*pb2[t+256] + g3*pb3[t+256];
  }
}

// ---------- register-GEMM core for the tiny weight-fuse GEMMs ----------
__device__ __forceinline__ void mfma_2x4_k(const short* a0, const short* a1,
    const short* b0, const short* b1, const short* b2, const short* b3,
    int K, f32x4 acc[2][4])
{
  for (int k0 = 0; k0 < K; k0 += 32){
    bf16x8 av0 = *(const bf16x8*)(a0 + k0);
    bf16x8 av1 = *(const bf16x8*)(a1 + k0);
    bf16x8 bv0 = *(const bf16x8*)(b0 + k0);
    bf16x8 bv1 = *(const bf16x8*)(b1 + k0);
    bf16x8 bv2 = *(const bf16x8*)(b2 + k0);
    bf16x8 bv3 = *(const bf16x8*)(b3 + k0);
    acc[0][0] = __builtin_amdgcn_mfma_f32_16x16x32_bf16(av0, bv0, acc[0][0],0,0,0);
    acc[0][1] = __builtin_amdgcn_mfma_f32_16x16x32_bf16(av0, bv1, acc[0][1],0,0,0);
    acc[0][2] = __builtin_amdgcn_mfma_f32_16x16x32_bf16(av0, bv2, acc[0][2],0,0,0);
    acc[0][3] = __builtin_amdgcn_mfma_f32_16x16x32_bf16(av0, bv3, acc[0][3],0,0,0);
    acc[1][0] = __builtin_amdgcn_mfma_f32_16x16x32_bf16(av1, bv0, acc[1][0],0,0,0);
    acc[1][1] = __builtin_amdgcn_mfma_f32_16x16x32_bf16(av1, bv1, acc[1][1],0,0,0);
    acc[1][2] = __builtin_amdgcn_mfma_f32_16x16x32_bf16(av1, bv2, acc[1][2],0,0,0);
    acc[1][3] = __builtin_amdgcn_mfma_f32_16x16x32_bf16(av1, bv3, acc[1][3],0,0,0);
  }
}

// ---------- merged weight-fuse: z<4 -> W_xz[g]; z>=4 -> Wog[g] ----------
__global__ __launch_bounds__(256) void k_wfuse(const short* __restrict__ inp_bf,
    const short* __restrict__ wpreT, const short* __restrict__ postw_bf,
    const short* __restrict__ woutT, const float* __restrict__ gains,
    short* __restrict__ wxz, short* __restrict__ wogc)
{
  int z = blockIdx.z; int g = z & 3, which = z >> 2;
  int bn = blockIdx.x * 64, bm = blockIdx.y * 128;
  int lane = threadIdx.x & 63, wave = threadIdx.x >> 6;
  int mr = lane & 15, qk = (lane >> 4) * 8, quad = lane >> 4;
  const short* Am = which ? (postw_bf + g*262144) : inp_bf;
  const short* Bm = which ? woutT : (wpreT + g*262144);
  const short* a0 = Am + (bm + wave*32 + mr)*512 + qk;
  const short* a1 = a0 + 16*512;
  const short* b0 = Bm + (bn +  0 + mr)*512 + qk;
  const short* b1 = Bm + (bn + 16 + mr)*512 + qk;
  const short* b2 = Bm + (bn + 32 + mr)*512 + qk;
  const short* b3 = Bm + (bn + 48 + mr)*512 + qk;
  f32x4 acc[2][4] = {};
  mfma_2x4_k(a0, a1, b0, b1, b2, b3, 512, acc);
  float gain = which ? gains[g] : 1.f;
  #pragma unroll
  for (int s=0;s<2;s++)
    #pragma unroll
    for (int t=0;t<4;t++)
      #pragma unroll
      for (int r=0;r<4;r++){
        int row = bm + wave*32 + s*16 + quad*4 + r;
        int col = bn + t*16 + mr;
        if (which) wogc[row*2048 + g*512 + col] = f2bf(gain * acc[s][t][r]);
        else       wxz[g*262144 + row*512 + col] = f2bf(acc[s][t][r]);
      }
}

// ---------- GEMM1: 256x128 tile, BK=32, K=512 (NT=16), grid 1568, XCD-swizzled ----------
// xz[(g*512+b)*49+l][ch] = tok[b][perm_g(l)][:] @ W_xz[g]^T + b_xz[g]
__global__ __launch_bounds__(512) void k_gemm1(const short* __restrict__ tok,
    const short* __restrict__ wxz, const float* __restrict__ bxz, short* __restrict__ xz)
{
  __shared__ __align__(16) short S[24576];    // 48 KB: 2 buf x (A 16KB | B 8KB)
  int bid = blockIdx.x;                       // 1568 = 8 * 196, bijective XCD swizzle
  int swz = (bid & 7) * 196 + (bid >> 3);
  int g = swz / 392, rem = swz - g*392;
  int bm = (rem >> 2) * 256, bn = (rem & 3) * 128;
  int tid = threadIdx.x, lane = tid & 63, w = tid >> 6;

  int rl = lane >> 2;                                 // row within 16-row unit
  int gch = ((lane & 3) ^ ((lane >> 3) & 3)) * 8;     // pre-swizzled global chunk
  const short* aU[2];
  #pragma unroll
  for (int j = 0; j < 2; ++j){
    int grow = bm + w*32 + j*16 + rl;
    int b = grow / 49, l49 = grow - b*49;
    int sl = perm_idx(g, l49);
    aU[j] = tok + ((size_t)(b*49 + sl))*512 + gch;
  }
  const short* bU = wxz + (size_t)g*262144 + (size_t)(bn + w*16 + rl)*512 + gch;

  f32x4 acc[4][4] = {};
  kcore256x128<16>(aU[0], aU[1], bU, S, w, lane, acc);

  int wr = w >> 1, wc = w & 1, mr = lane & 15, quad = lane >> 4;
  #pragma unroll
  for (int mf = 0; mf < 4; ++mf)
    #pragma unroll
    for (int rr = 0; rr < 4; ++rr){
      int row = bm + wr*64 + mf*16 + quad*4 + rr;
      int b = row / 49, l = row - b*49;
      size_t orow = ((size_t)(g*512 + b)*49 + l)*512;
      #pragma unroll
      for (int nf = 0; nf < 4; ++nf){
        int col = bn + wc*64 + nf*16 + mr;
        xz[orow + col] = f2bf(acc[mf][nf][rr] + bxz[g*512 + col]);
      }
    }
}

// ---------- k_conv: depthwise conv3 + SiLU, fully parallel ----------
__global__ __launch_bounds__(256) void k_conv(const short* __restrict__ xz,
    const float* __restrict__ cxw, const float* __restrict__ cxb,
    const float* __restrict__ czw, const float* __restrict__ czb,
    short* __restrict__ ycat)
{
  int t = threadIdx.x;
  int oct = t & 63, lstart = t >> 6;
  int ch0 = oct * 8;
  bool isx = ch0 < 256;
  int cc0 = isx ? ch0 : ch0 - 256;
  const float* wsrc = isx ? cxw : czw;
  const float* bsrc = isx ? cxb : czb;
  float w0[8], w1[8], w2[8], bb[8];
  #pragma unroll
  for (int e=0;e<8;e++){
    w0[e] = wsrc[(cc0+e)*3]; w1[e] = wsrc[(cc0+e)*3+1]; w2[e] = wsrc[(cc0+e)*3+2];
    bb[e] = bsrc[cc0+e];
  }
  int gb = blockIdx.x; int g = gb >> 9, b = gb & 511;
  const short* src = xz + (size_t)gb*25088 + ch0;
  short* dst = ycat + (size_t)(b*49)*2048 + g*512 + ch0;
  for (int l = lstart; l < 49; l += 4){
    bf16x8 vm = {}, vp = {};
    bf16x8 v0 = *(const bf16x8*)(src + l*512);
    if (l > 0)  vm = *(const bf16x8*)(src + (l-1)*512);
    if (l < 48) vp = *(const bf16x8*)(src + (l+1)*512);
    short ov[8];
    #pragma unroll
    for (int e=0;e<8;e++){
      float x = w0[e]*bf2f(vm[e]) + w1[e]*bf2f(v0[e]) + w2[e]*bf2f(vp[e]) + bb[e];
      ov[e] = f2bf(x / (1.f + __expf(-x)));
    }
    *(bf16x8*)(dst + l*2048) = *(bf16x8*)ov;
  }
}

// ---------- k_xproj: x_proj GEMM + LN + dt GEMM + softplus ----------
__global__ __launch_bounds__(256) void k_xproj(const short* __restrict__ ycat,
    const short* __restrict__ xpw_bf, const float* __restrict__ lnw, const float* __restrict__ lnb,
    const short* __restrict__ dtw_bf, const float* __restrict__ dtb,
    short* __restrict__ dtln, float* __restrict__ bc)
{
  // LDS: xd f32 [128][52] = 26624 B ; xln_bf bf16 [128][40] = 10240 B
  __shared__ __align__(16) char smem[36864];
  float* xd = (float*)smem;
  short* xln = (short*)(smem + 26624);

  int bm = blockIdx.x * 128;
  int g = bm / 25088;                   // uniform per block (128 | 25088)
  int tid = threadIdx.x, lane = tid & 63, w = tid >> 6;
  int mr = lane & 15, quad = lane >> 4, qk = quad * 8;

  // ---- phase 1: x_dbl = u @ xpw^T  (tile 128x48, K=256) ----
  {
    const short* ap[2];
    #pragma unroll
    for (int s=0;s<2;s++)
      ap[s] = ycat + (size_t)(bm - g*25088 + w*32 + s*16 + mr)*2048 + g*512 + qk;
    f32x4 acc[2][3] = {};
    #pragma unroll
    for (int k0 = 0; k0 < 256; k0 += 32){
      bf16x8 av[2];
      #pragma unroll
      for (int s=0;s<2;s++) av[s] = *(const bf16x8*)(ap[s] + k0);
      #pragma unroll
      for (int t=0;t<3;t++){
        bf16x8 bv = *(const bf16x8*)(xpw_bf + (t*16 + mr)*256 + qk + k0);
        #pragma unroll
        for (int s=0;s<2;s++)
          acc[s][t] = __builtin_amdgcn_mfma_f32_16x16x32_bf16(av[s], bv, acc[s][t],0,0,0);
      }
    }
    #pragma unroll
    for (int s=0;s<2;s++)
      #pragma unroll
      for (int t=0;t<3;t++)
        #pragma unroll
        for (int r=0;r<4;r++)
          xd[(w*32 + s*16 + quad*4 + r)*52 + t*16 + mr] = acc[s][t][r];
  }
  __syncthreads();

  // ---- phase 2: LN per row (threads 0..127), write dt-cols to xln (bf16) + B/C to global ----
  if (tid < 128){
    f32x4* xr4 = (f32x4*)(xd + tid*52);
    f32x4 s = xr4[0];
    #pragma unroll
    for (int i=1;i<12;i++) s += xr4[i];
    float m = (s[0]+s[1]+s[2]+s[3]) * (1.f/48.f);
    f32x4 vs = {};
    #pragma unroll
    for (int i=0;i<12;i++){ f32x4 d = xr4[i] - m; vs += d*d; }
    float var = (vs[0]+vs[1]+vs[2]+vs[3]) * (1.f/48.f);
    float rstd = rsqrtf(var + 1e-5f);
    const f32x4* g4 = (const f32x4*)lnw;
    const f32x4* b4 = (const f32x4*)lnb;
    uint32_t* xlr = (uint32_t*)(xln + tid*40);
    #pragma unroll
    for (int i=0;i<8;i++){       // cols 0..31 -> xln bf16
      f32x4 v = (xr4[i] - m) * rstd * g4[i] + b4[i];
      xlr[2*i]   = (uint32_t)(uint16_t)f2bf(v[0]) | ((uint32_t)(uint16_t)f2bf(v[1]) << 16);
      xlr[2*i+1] = (uint32_t)(uint16_t)f2bf(v[2]) | ((uint32_t)(uint16_t)f2bf(v[3]) << 16);
    }
    f32x4* bco = (f32x4*)(bc + (size_t)(bm + tid)*16);
    #pragma unroll
    for (int i=8;i<12;i++)       // cols 32..47 -> bc f32
      bco[i-8] = (xr4[i] - m) * rstd * g4[i] + b4[i];
  }
  __syncthreads();

  // ---- phase 3: dt = xln[:,0:32] @ dtw^T (K=32, N=256) + bias + softplus -> dtln ----
  // softplus via hardware exp2/log2 path; for x>15 select x (err << bf16 ulp).
  {
    bf16x8 a[2];
    #pragma unroll
    for (int s=0;s<2;s++)
      a[s] = *(const bf16x8*)(xln + (w*32 + s*16 + mr)*40 + qk);
    #pragma unroll 4
    for (int nt=0; nt<16; nt++){
      int col = nt*16 + mr;
      bf16x8 bv = *(const bf16x8*)(dtw_bf + col*32 + qk);
      float dtbv = dtb[col];
      #pragma unroll
      for (int s=0;s<2;s++){
        f32x4 acc = {};
        acc = __builtin_amdgcn_mfma_f32_16x16x32_bf16(a[s], bv, acc,0,0,0);
        #pragma unroll
        for (int r=0;r<4;r++){
          int grow = bm + w*32 + s*16 + quad*4 + r;
          float dtv = acc[r] + dtbv;
          float e  = __expf(dtv);
          float sp = __logf(1.f + e);
          float delta = (dtv > 15.f) ? dtv : sp;
          dtln[(size_t)grow*256 + col] = f2bf(delta);
        }
      }
    }
  }
}

// ---------- k_scan: selective scan, one block per gb, u->y in place ----------
__global__ __launch_bounds__(256) void k_scan(short* __restrict__ ycat,
    const short* __restrict__ dtln, const float* __restrict__ bc,
    const float* __restrict__ Alog, const float* __restrict__ Dp)
{
  __shared__ __align__(16) float bcs[784];   // [49][16]
  int gb = blockIdx.x; int g = gb >> 9, b = gb & 511;
  int d = threadIdx.x;
  if (d < 196) ((f32x4*)bcs)[d] = ((const f32x4*)(bc + (size_t)gb*784))[d];
  __syncthreads();

  float A[8], h[8];
  {
    f32x4 a0 = *(const f32x4*)(Alog + d*8);
    f32x4 a1 = *(const f32x4*)(Alog + d*8 + 4);
    #pragma unroll
    for (int n=0;n<4;n++){ A[n] = -__expf(a0[n]); A[n+4] = -__expf(a1[n]); h[n]=0.f; h[n+4]=0.f; }
  }
  float Dpar = Dp[d];

  const short* dptr = dtln + (size_t)gb*49*256 + d;
  short* uptr = ycat + (size_t)(b*49)*2048 + g*512 + d;

  float dn = bf2f(dptr[0]);
  float un = bf2f(uptr[0]);
  for (int l=0;l<49;l++){
    float delta = dn, u = un;
    if (l < 48){ dn = bf2f(dptr[(l+1)*256]); un = bf2f(uptr[(l+1)*2048]); }
    const f32x4* bcr = (const f32x4*)(bcs + l*16);
    f32x4 B0 = bcr[0], B1 = bcr[1], C0 = bcr[2], C1 = bcr[3];
    float du = delta * u;
    float y = 0.f;
    #pragma unroll
    for (int n=0;n<4;n++){
      h[n] = h[n]*__expf(delta*A[n]) + du*B0[n];
      y += h[n]*C0[n];
    }
    #pragma unroll
    for (int n=0;n<4;n++){
      h[n+4] = h[n+4]*__expf(delta*A[n+4]) + du*B1[n];
      y += h[n+4]*C1[n];
    }
    uptr[l*2048] = f2bf(y + Dpar*u);
  }
}

// ---------- final GEMM: 256x256 tile, BK=32, K=2048 (NT=64), grid 196 ----------
__global__ __launch_bounds__(512) void k_gemmF(const short* __restrict__ ycat,
    const short* __restrict__ wogc, const float* __restrict__ biasc,
    float* __restrict__ out)
{
  __shared__ __align__(16) short S[32768];    // 64 KB: 2 buf x (A 16KB | B 16KB)
  int bid = blockIdx.x;                       // 196 = 98 bm x 2 bn (single round)
  int bm = (bid >> 1) * 256, bn = (bid & 1) * 256;
  int tid = threadIdx.x, lane = tid & 63, w = tid >> 6;

  int rl = lane >> 2;                                 // row within 16-row unit
  int gch = ((lane & 3) ^ ((lane >> 3) & 3)) * 8;     // pre-swizzled global chunk
  const short* aU0 = ycat + (size_t)(bm + w*32      + rl)*2048 + gch;
  const short* aU1 = ycat + (size_t)(bm + w*32 + 16 + rl)*2048 + gch;
  const short* bU0 = wogc + (size_t)(bn + w*32      + rl)*2048 + gch;
  const short* bU1 = wogc + (size_t)(bn + w*32 + 16 + rl)*2048 + gch;

  f32x4 acc[8][4] = {};
  kcore256<64>(aU0, aU1, bU0, bU1, S, w, lane, acc);

  int wr = w >> 2, wc = w & 3, mr = lane & 15, quad = lane >> 4;
  #pragma unroll
  for (int mf = 0; mf < 8; ++mf)
    #pragma unroll
    for (int rr = 0; rr < 4; ++rr){
      int row = bm + wr*128 + mf*16 + quad*4 + rr;
      float* orow = out + (size_t)row*512;
      #pragma unroll
      for (int nf = 0; nf < 4; ++nf){
        int col = bn + wc*64 + nf*16 + mr;
        orow[col] = acc[mf][nf][rr] + biasc[col];
      }
    }
}

// ---------- launch ----------
extern "C" void kernel_launch(void* const* d_in, const int* in_sizes, int n_in,
                              void* d_out, int out_size, void* d_ws, size_t ws_size,
                              hipStream_t stream)
{
  const float* tokens    = (const float*)d_in[0];
  const float* pre_w[4]  = {(const float*)d_in[1], (const float*)d_in[3], (const float*)d_in[5], (const float*)d_in[7]};
  const float* pre_b[4]  = {(const float*)d_in[2], (const float*)d_in[4], (const float*)d_in[6], (const float*)d_in[8]};
  const float* post_w[4] = {(const float*)d_in[9], (const float*)d_in[11], (const float*)d_in[13], (const float*)d_in[15]};
  const float* post_b[4] = {(const float*)d_in[10], (const float*)d_in[12], (const float*)d_in[14], (const float*)d_in[16]};
  const float* in_proj   = (const float*)d_in[17];
  const float* conv_x_w  = (const float*)d_in[18];
  const float* conv_x_b  = (const float*)d_in[19];
  const float* conv_z_w  = (const float*)d_in[20];
  const float* conv_z_b  = (const float*)d_in[21];
  const float* x_proj_w  = (const float*)d_in[22];
  const float* ln_w      = (const float*)d_in[23];
  const float* ln_b      = (const float*)d_in[24];
  const float* dt_proj_w = (const float*)d_in[25];
  const float* dt_proj_b = (const float*)d_in[26];
  const float* A_log     = (const float*)d_in[27];
  const float* D_param   = (const float*)d_in[28];
  const float* out_proj  = (const float*)d_in[29];
  const float* gate_log  = (const float*)d_in[30];

  char* ws = (char*)d_ws;
  size_t o = 0;
  short* tok_bf   = (short*)(ws + o); o += 25690112;   // 12845056 bf16
  short* wpreT    = (short*)(ws + o); o += 2097152;    // 4x 512x512 bf16 (transposed)
  short* inp_bf   = (short*)(ws + o); o += 524288;
  short* postw_bf = (short*)(ws + o); o += 2097152;
  short* woutT    = (short*)(ws + o); o += 524288;
  short* wogc     = (short*)(ws + o); o += 2097152;    // 512 x 2048 bf16
  short* wxz      = (short*)(ws + o); o += 2097152;    // 4x 512x512 bf16
  short* xpw_bf   = (short*)(ws + o); o += 24576;      // 48x256 bf16
  short* dtw_bf   = (short*)(ws + o); o += 16384;      // 256x32 bf16
  float* bxz      = (float*)(ws + o); o += 8192;
  float* gains    = (float*)(ws + o); o += 64;
  float* biasc    = (float*)(ws + o); o += 2048;
  size_t xz_off = o;
  short* xz       = (short*)(ws + o); o += 102760448;  // 2048*49*512 bf16
  short* ycat     = (short*)(ws + o); o += 102760448;  // 25088 x 2048 bf16
  // dtln (51.4 MB) + bc (6.4 MB) alias the xz region: xz is dead after k_conv.
  short* dtln     = (short*)(ws + xz_off);
  float* bc       = (float*)(ws + xz_off + 51380224);

  k_conv_all<<<1300, 256, 0, stream>>>(in_proj,
      post_w[0], post_w[1], post_w[2], post_w[3],
      x_proj_w, dt_proj_w, inp_bf, postw_bf, xpw_bf, dtw_bf);
  k_transp<<<dim3(64,5), 256, 0, stream>>>(pre_w[0], pre_w[1], pre_w[2], pre_w[3],
      out_proj, wpreT, woutT);
  k_tok<<<12544, 256, 0, stream>>>(tokens, tok_bf);
  k_bxz_gains<<<9, 256, 0, stream>>>(in_proj, pre_b[0], pre_b[1], pre_b[2], pre_b[3],
      gate_log, post_b[0], post_b[1], post_b[2], post_b[3], bxz, gains, biasc);
  k_wfuse<<<dim3(8,4,8), 256, 0, stream>>>(inp_bf, wpreT, postw_bf, woutT, gains, wxz, wogc);
  k_gemm1<<<dim3(1568), 512, 0, stream>>>(tok_bf, wxz, bxz, xz);
  k_conv<<<2048, 256, 0, stream>>>(xz, conv_x_w, conv_x_b, conv_z_w, conv_z_b, ycat);
  k_xproj<<<784, 256, 0, stream>>>(ycat, xpw_bf, ln_w, ln_b, dtw_bf, dt_proj_b, dtln, bc);
  k_scan<<<2048, 256, 0, stream>>>(ycat, dtln, bc, A_log, D_param);
  k_gemmF<<<dim3(196), 512, 0, stream>>>(ycat, wogc, biasc, (float*)d_out);
}

// Round 11
// 453.117 us; speedup vs baseline: 1.1631x; 1.0657x over previous
//
#include <hip/hip_runtime.h>
#include <stdint.h>

// ---------- types ----------
typedef __attribute__((ext_vector_type(8))) short bf16x8;   // 8 bf16 in 4 VGPRs
typedef __attribute__((ext_vector_type(4))) float f32x4;

__device__ __forceinline__ float bf2f(short u){
  union { float f; uint32_t i; } v; v.i = ((uint32_t)(uint16_t)u) << 16; return v.f;
}
__device__ __forceinline__ short f2bf(float x){
  union { float f; uint32_t i; } v; v.f = x;
  uint32_t r = v.i + 0x7FFFu + ((v.i >> 16) & 1u);   // RNE
  return (short)(r >> 16);
}

// async global->LDS, 16B per lane; LDS dest = wave-uniform base + lane*16
__device__ __forceinline__ void gl_lds16(const short* g, short* l){
  __builtin_amdgcn_global_load_lds(
      (__attribute__((address_space(1))) void*)(short*)g,
      (__attribute__((address_space(3))) void*)l, 16, 0, 0);
}

// ---------- permutation tables (WIN=7, compile-time) ----------
__device__ const int d_DIAG[49] = {0,1,7,2,8,14,3,9,15,21,4,10,16,22,28,5,11,17,23,29,35,
  6,12,18,24,30,36,42,13,19,25,31,37,43,20,26,32,38,44,27,33,39,45,34,40,46,41,47,48};
__device__ const int d_ANTI[49] = {6,5,13,4,12,20,3,11,19,27,2,10,18,26,34,1,9,17,25,33,41,
  0,8,16,24,32,40,48,7,15,23,31,39,47,14,22,30,38,46,21,29,37,45,28,36,44,35,43,42};

__device__ __forceinline__ int perm_idx(int g, int l){
  if (g == 0) return l;
  if (g == 1) return (l % 7) * 7 + l / 7;  // V_IDX
  if (g == 2) return d_DIAG[l];
  return d_ANTI[l];
}

// ---------- 256x128 K-loop core: BK=32, 8 waves (4M x 2N), 48KB LDS ----------
// LDS buffer stride 12288 shorts (24KB): A [256r][32] at +0, B [128r][32] at +8192.
// Per wave per tile: 3 stage units (A rows w*32..+31 x2, B rows w*16..+15 x1).
// Boundary: barrier1; stage A(t+2)x2; vmcnt(2) (newest 2 = A(t+2) in flight,
// A(t+1)+B(t+1) landed); barrier2. In-loop: stage B(t+1) (dest buf not read).
// Chunk XOR-swizzle (proven r2/r3): LDS chunk s of row r holds global chunk
// s ^ ((r>>1)&3); reads use quad ^ ((mr>>1)&3) -> conflict-free ds_read_b128.
template<int NT>
__device__ __forceinline__ void kcore256x128(
    const short* aU0, const short* aU1, const short* bU,
    short* S, int w, int lane, f32x4 acc[4][4])
{
  int wr = w >> 1, wc = w & 1;
  int mr = lane & 15, quad = lane >> 4;
  int sw = (quad ^ ((mr >> 1) & 3)) * 8;     // swizzled chunk offset (shorts)
  auto STAGE_A = [&](int t){
    short* base = S + (t & 1) * 12288;
    gl_lds16(aU0 + t*32, base + (w*32)*32);
    gl_lds16(aU1 + t*32, base + (w*32 + 16)*32);
  };
  auto STAGE_B = [&](int t){
    short* base = S + (t & 1) * 12288;
    gl_lds16(bU + t*32, base + 8192 + (w*16)*32);
  };
  STAGE_A(0); STAGE_B(0);
  if (NT > 1) STAGE_A(1);
  asm volatile("s_waitcnt vmcnt(2)" ::: "memory");   // tile 0's 3 loads done
  __builtin_amdgcn_s_barrier();
  for (int t = 0; t < NT; ++t){
    const short* Ab = S + (t & 1) * 12288;
    const short* Bb = Ab + 8192;
    bf16x8 bfr[4];
    #pragma unroll
    for (int nf = 0; nf < 4; ++nf)
      bfr[nf] = *(const bf16x8*)(Bb + (wc*64 + nf*16 + mr)*32 + sw);
    #pragma unroll
    for (int ph = 0; ph < 4; ++ph){
      bf16x8 af = *(const bf16x8*)(Ab + (wr*64 + ph*16 + mr)*32 + sw);
      if (ph == 1 && t+1 < NT) STAGE_B(t+1);       // B of t+1 -> buf (t+1)&1
      #pragma unroll
      for (int nf = 0; nf < 4; ++nf)
        acc[ph][nf] = __builtin_amdgcn_mfma_f32_16x16x32_bf16(af, bfr[nf], acc[ph][nf],0,0,0);
    }
    __builtin_amdgcn_s_barrier();            // all waves done reading buf t&1
    if (t+2 < NT){
      STAGE_A(t+2);                          // A of t+2 -> just-freed buf
      asm volatile("s_waitcnt vmcnt(2)" ::: "memory");   // A(t+1)+B(t+1) landed
    } else if (t+1 < NT){
      asm volatile("s_waitcnt vmcnt(0)" ::: "memory");   // tail drain (once)
    }
    __builtin_amdgcn_s_barrier();            // all waves' t+1 loads visible
  }
}

// ---------- prep: plain f32->bf16 converts (in_proj, post x4, x_proj_w, dt_proj_w) ----------
__global__ __launch_bounds__(256) void k_conv_all(
    const float* __restrict__ in_proj,
    const float* __restrict__ pw0, const float* __restrict__ pw1,
    const float* __restrict__ pw2, const float* __restrict__ pw3,
    const float* __restrict__ xpw, const float* __restrict__ dtw,
    short* __restrict__ inp_bf, short* __restrict__ postw_bf,
    short* __restrict__ xpw_bf, short* __restrict__ dtw_bf)
{
  int q = blockIdx.x*256 + threadIdx.x;   // quad index, total 332800
  const float* src; short* dst; int off;
  if (q < 65536){ src = in_proj; dst = inp_bf; off = q; }
  else if (q < 65536 + 262144){
    int r = q - 65536; int g = r >> 16; int loc = r & 65535;
    src = (g==0)?pw0:(g==1)?pw1:(g==2)?pw2:pw3;
    dst = postw_bf + g*262144; off = loc;
  }
  else if (q < 65536 + 262144 + 3072){ src = xpw; dst = xpw_bf; off = q - (65536+262144); }
  else { src = dtw; dst = dtw_bf; off = q - (65536+262144+3072); }
  float4 v = *(const float4*)(src + off*4);
  uint32_t p0 = (uint32_t)(uint16_t)f2bf(v.x) | ((uint32_t)(uint16_t)f2bf(v.y) << 16);
  uint32_t p1 = (uint32_t)(uint16_t)f2bf(v.z) | ((uint32_t)(uint16_t)f2bf(v.w) << 16);
  uint2 p; p.x = p0; p.y = p1;
  *(uint2*)(dst + off*4) = p;
}

// ---------- prep: LDS-tiled transpose+convert (pre_w x4 -> wpreT, out_proj -> woutT) ----------
__global__ __launch_bounds__(256) void k_transp(
    const float* __restrict__ pw0, const float* __restrict__ pw1,
    const float* __restrict__ pw2, const float* __restrict__ pw3,
    const float* __restrict__ outp,
    short* __restrict__ wpreT, short* __restrict__ woutT)
{
  __shared__ float tile[64][65];
  int which = blockIdx.y;
  const float* src = (which==0)?pw0:(which==1)?pw1:(which==2)?pw2:(which==3)?pw3:outp;
  short* dst = (which < 4) ? (wpreT + which*262144) : woutT;
  int bi = blockIdx.x >> 3, bj = blockIdx.x & 7;
  int r0 = bi*64, c0 = bj*64;
  int t = threadIdx.x;
  int row = t >> 2, cg = t & 3;
  const float4* s4 = (const float4*)(src + (r0+row)*512 + c0 + cg*16);
  #pragma unroll
  for (int i=0;i<4;i++){
    float4 v = s4[i];
    tile[row][cg*16 + i*4 + 0] = v.x;
    tile[row][cg*16 + i*4 + 1] = v.y;
    tile[row][cg*16 + i*4 + 2] = v.z;
    tile[row][cg*16 + i*4 + 3] = v.w;
  }
  __syncthreads();
  int oc = t >> 2;
  short tmp[16];
  #pragma unroll
  for (int i=0;i<16;i++) tmp[i] = f2bf(tile[cg*16 + i][oc]);
  short* dp = dst + (size_t)(c0+oc)*512 + r0 + cg*16;
  *(bf16x8*)(dp)     = *(bf16x8*)tmp;
  *(bf16x8*)(dp + 8) = *((bf16x8*)tmp + 1);
}

__global__ __launch_bounds__(256) void k_tok(const float* __restrict__ t, short* __restrict__ o){
  int i = (blockIdx.x*256 + threadIdx.x) * 4;
  float4 v = *(const float4*)(t + i);
  uint32_t p0 = (uint32_t)(uint16_t)f2bf(v.x) | ((uint32_t)(uint16_t)f2bf(v.y) << 16);
  uint32_t p1 = (uint32_t)(uint16_t)f2bf(v.z) | ((uint32_t)(uint16_t)f2bf(v.w) << 16);
  uint2 p; p.x = p0; p.y = p1;
  *(uint2*)(o + i) = p;
}

// ---------- prep: b_xz (blocks 0-7) + gains/biasc (block 8) ----------
__global__ __launch_bounds__(256) void k_bxz_gains(const float* __restrict__ in_proj,
    const float* __restrict__ b0, const float* __restrict__ b1,
    const float* __restrict__ b2, const float* __restrict__ b3,
    const float* __restrict__ gl,
    const float* __restrict__ pb0, const float* __restrict__ pb1,
    const float* __restrict__ pb2, const float* __restrict__ pb3,
    float* __restrict__ bxz, float* __restrict__ gains, float* __restrict__ biasc)
{
  if (blockIdx.x < 8){
    int idx = blockIdx.x*256 + threadIdx.x;   // 0..2047
    int g = idx >> 9, i = idx & 511;
    const float* bb = (g==0)?b0:(g==1)?b1:(g==2)?b2:b3;
    float s = 0.f;
    for (int t=0;t<512;t++) s += in_proj[i*512+t]*bb[t];
    bxz[idx] = s;
  } else {
    float m = fmaxf(fmaxf(gl[0], gl[1]), fmaxf(gl[2], gl[3]));
    float e0 = expf(gl[0]-m), e1 = expf(gl[1]-m), e2 = expf(gl[2]-m), e3 = expf(gl[3]-m);
    float s = e0+e1+e2+e3;
    float g0 = e0/s, g1 = e1/s, g2 = e2/s, g3 = e3/s;
    int t = threadIdx.x;
    if (t == 0){ gains[0]=g0; gains[1]=g1; gains[2]=g2; gains[3]=g3; }
    biasc[t]     = g0*pb0[t]     + g1*pb1[t]     + g2*pb2[t]     + g3*pb3[t];
    biasc[t+256] = g0*pb0[t+256] + g1*pb1[t+256] + g2*pb2[t+256] + g3*pb3[t+256];
  }
}

// ---------- register-GEMM core for the tiny weight-fuse GEMMs ----------
__device__ __forceinline__ void mfma_2x4_k(const short* a0, const short* a1,
    const short* b0, const short* b1, const short* b2, const short* b3,
    int K, f32x4 acc[2][4])
{
  for (int k0 = 0; k0 < K; k0 += 32){
    bf16x8 av0 = *(const bf16x8*)(a0 + k0);
    bf16x8 av1 = *(const bf16x8*)(a1 + k0);
    bf16x8 bv0 = *(const bf16x8*)(b0 + k0);
    bf16x8 bv1 = *(const bf16x8*)(b1 + k0);
    bf16x8 bv2 = *(const bf16x8*)(b2 + k0);
    bf16x8 bv3 = *(const bf16x8*)(b3 + k0);
    acc[0][0] = __builtin_amdgcn_mfma_f32_16x16x32_bf16(av0, bv0, acc[0][0],0,0,0);
    acc[0][1] = __builtin_amdgcn_mfma_f32_16x16x32_bf16(av0, bv1, acc[0][1],0,0,0);
    acc[0][2] = __builtin_amdgcn_mfma_f32_16x16x32_bf16(av0, bv2, acc[0][2],0,0,0);
    acc[0][3] = __builtin_amdgcn_mfma_f32_16x16x32_bf16(av0, bv3, acc[0][3],0,0,0);
    acc[1][0] = __builtin_amdgcn_mfma_f32_16x16x32_bf16(av1, bv0, acc[1][0],0,0,0);
    acc[1][1] = __builtin_amdgcn_mfma_f32_16x16x32_bf16(av1, bv1, acc[1][1],0,0,0);
    acc[1][2] = __builtin_amdgcn_mfma_f32_16x16x32_bf16(av1, bv2, acc[1][2],0,0,0);
    acc[1][3] = __builtin_amdgcn_mfma_f32_16x16x32_bf16(av1, bv3, acc[1][3],0,0,0);
  }
}

// ---------- merged weight-fuse: z<4 -> W_xz[g]; z>=4 -> Wog[g] ----------
__global__ __launch_bounds__(256) void k_wfuse(const short* __restrict__ inp_bf,
    const short* __restrict__ wpreT, const short* __restrict__ postw_bf,
    const short* __restrict__ woutT, const float* __restrict__ gains,
    short* __restrict__ wxz, short* __restrict__ wogc)
{
  int z = blockIdx.z; int g = z & 3, which = z >> 2;
  int bn = blockIdx.x * 64, bm = blockIdx.y * 128;
  int lane = threadIdx.x & 63, wave = threadIdx.x >> 6;
  int mr = lane & 15, qk = (lane >> 4) * 8, quad = lane >> 4;
  const short* Am = which ? (postw_bf + g*262144) : inp_bf;
  const short* Bm = which ? woutT : (wpreT + g*262144);
  const short* a0 = Am + (bm + wave*32 + mr)*512 + qk;
  const short* a1 = a0 + 16*512;
  const short* b0 = Bm + (bn +  0 + mr)*512 + qk;
  const short* b1 = Bm + (bn + 16 + mr)*512 + qk;
  const short* b2 = Bm + (bn + 32 + mr)*512 + qk;
  const short* b3 = Bm + (bn + 48 + mr)*512 + qk;
  f32x4 acc[2][4] = {};
  mfma_2x4_k(a0, a1, b0, b1, b2, b3, 512, acc);
  float gain = which ? gains[g] : 1.f;
  #pragma unroll
  for (int s=0;s<2;s++)
    #pragma unroll
    for (int t=0;t<4;t++)
      #pragma unroll
      for (int r=0;r<4;r++){
        int row = bm + wave*32 + s*16 + quad*4 + r;
        int col = bn + t*16 + mr;
        if (which) wogc[row*2048 + g*512 + col] = f2bf(gain * acc[s][t][r]);
        else       wxz[g*262144 + row*512 + col] = f2bf(acc[s][t][r]);
      }
}

// ---------- GEMM1+conv fused: BM=245 (5 whole b-groups, padded to 256 compute
// rows), BN=128, BK=32, K=512 (NT=16), grid 1648 = 4g x 103blk x 4bn,
// XCD-swizzled (1648 = 8*206). Epilogue: bias -> depthwise conv3 -> SiLU via
// LDS tile (reused staging LDS, stride 72 shorts = 144B: keeps every
// bf16x8 read 16B-aligned [r8 bug: stride 68 broke alignment on odd rows]
// and rotates banks by 4/row), writes ycat directly. xz + k_conv eliminated.
__global__ __launch_bounds__(512) void k_gemm1c(const short* __restrict__ tok,
    const short* __restrict__ wxz, const float* __restrict__ bxz,
    const float* __restrict__ cxw, const float* __restrict__ cxb,
    const float* __restrict__ czw, const float* __restrict__ czb,
    short* __restrict__ ycat)
{
  __shared__ __align__(16) short S[24576];    // 48 KB staging; reused as conv tile [256][72]
  int bid = blockIdx.x;                       // 1648 = 8 * 206, bijective XCD swizzle
  int swz = (bid & 7) * 206 + (bid >> 3);
  int g = swz / 412, rem = swz - g*412;
  int blk = rem >> 2, bn = (rem & 3) * 128;
  int bm = blk * 245;                         // multiple of 49 -> b-group aligned
  int nreal = min(245, 25088 - bm);           // last block has 98 real rows
  int tid = threadIdx.x, lane = tid & 63, w = tid >> 6;

  int rl = lane >> 2;                                 // row within 16-row unit
  int gch = ((lane & 3) ^ ((lane >> 3) & 3)) * 8;     // pre-swizzled global chunk
  const short* aU[2];
  #pragma unroll
  for (int j = 0; j < 2; ++j){
    int p = w*32 + j*16 + rl;
    int pr = (p < nreal) ? p : (nreal - 1);           // clamp padded rows
    int q49 = pr / 49;
    int l49 = pr - q49*49;
    int b = blk*5 + q49;
    int sl = perm_idx(g, l49);
    aU[j] = tok + ((size_t)(b*49 + sl))*512 + gch;
  }
  const short* bU = wxz + (size_t)g*262144 + (size_t)(bn + w*16 + rl)*512 + gch;

  f32x4 acc[4][4] = {};
  kcore256x128<16>(aU[0], aU[1], bU, S, w, lane, acc);

  // ---- fused epilogue: two 64-col halves; T = S reused, [256][72] shorts ----
  int wr = w >> 1, wc = w & 1, mr = lane & 15, quad = lane >> 4;
  int rowgrp = tid >> 3, oct = tid & 7;      // 64 row-groups x 8 col-octs
  #pragma unroll
  for (int h = 0; h < 2; ++h){
    if (wc == h){
      #pragma unroll
      for (int mf = 0; mf < 4; ++mf)
        #pragma unroll
        for (int nf = 0; nf < 4; ++nf)
          #pragma unroll
          for (int rr = 0; rr < 4; ++rr){
            int row = wr*64 + mf*16 + quad*4 + rr;
            int col = nf*16 + mr;
            S[row*72 + col] = f2bf(acc[mf][nf][rr] + bxz[g*512 + bn + h*64 + col]);
          }
    }
    __syncthreads();                         // tile half h visible
    int colbase = bn + h*64 + oct*8;         // global xz column (== ycat channel)
    bool isx = colbase < 256;
    const float* wsrc = isx ? cxw : czw;
    const float* bsrc = isx ? cxb : czb;
    int cc0 = isx ? colbase : colbase - 256;
    float w0[8], w1[8], w2[8], cb[8];
    #pragma unroll
    for (int e = 0; e < 8; ++e){
      w0[e] = wsrc[(cc0+e)*3]; w1[e] = wsrc[(cc0+e)*3+1]; w2[e] = wsrc[(cc0+e)*3+2];
      cb[e] = bsrc[cc0+e];
    }
    for (int i = 0; i < 4; ++i){
      int p = rowgrp + 64*i;
      if (p < nreal){
        int l = p - (p/49)*49;
        bf16x8 vm = {}, vp = {};
        bf16x8 v0 = *(const bf16x8*)(S + p*72 + oct*8);
        if (l > 0)  vm = *(const bf16x8*)(S + (p-1)*72 + oct*8);
        if (l < 48) vp = *(const bf16x8*)(S + (p+1)*72 + oct*8);
        short ov[8];
        #pragma unroll
        for (int e = 0; e < 8; ++e){
          float x = w0[e]*bf2f(vm[e]) + w1[e]*bf2f(v0[e]) + w2[e]*bf2f(vp[e]) + cb[e];
          ov[e] = f2bf(x / (1.f + __expf(-x)));
        }
        // ycat row = b*49 + l = bm + p (b-group aligned tiling)
        *(bf16x8*)(ycat + (size_t)(bm + p)*2048 + g*512 + colbase) = *(bf16x8*)ov;
      }
    }
    __syncthreads();                         // conv reads done before half 1 overwrites
  }
}

// ---------- k_xproj: x_proj GEMM + LN + dt GEMM + softplus ----------
__global__ __launch_bounds__(256) void k_xproj(const short* __restrict__ ycat,
    const short* __restrict__ xpw_bf, const float* __restrict__ lnw, const float* __restrict__ lnb,
    const short* __restrict__ dtw_bf, const float* __restrict__ dtb,
    short* __restrict__ dtln, float* __restrict__ bc)
{
  // LDS: xd f32 [128][52] = 26624 B ; xln_bf bf16 [128][40] = 10240 B
  __shared__ __align__(16) char smem[36864];
  float* xd = (float*)smem;
  short* xln = (short*)(smem + 26624);

  int bm = blockIdx.x * 128;
  int g = bm / 25088;                   // uniform per block (128 | 25088)
  int tid = threadIdx.x, lane = tid & 63, w = tid >> 6;
  int mr = lane & 15, quad = lane >> 4, qk = quad * 8;

  // ---- phase 1: x_dbl = u @ xpw^T  (tile 128x48, K=256) ----
  {
    const short* ap[2];
    #pragma unroll
    for (int s=0;s<2;s++)
      ap[s] = ycat + (size_t)(bm - g*25088 + w*32 + s*16 + mr)*2048 + g*512 + qk;
    f32x4 acc[2][3] = {};
    #pragma unroll
    for (int k0 = 0; k0 < 256; k0 += 32){
      bf16x8 av[2];
      #pragma unroll
      for (int s=0;s<2;s++) av[s] = *(const bf16x8*)(ap[s] + k0);
      #pragma unroll
      for (int t=0;t<3;t++){
        bf16x8 bv = *(const bf16x8*)(xpw_bf + (t*16 + mr)*256 + qk + k0);
        #pragma unroll
        for (int s=0;s<2;s++)
          acc[s][t] = __builtin_amdgcn_mfma_f32_16x16x32_bf16(av[s], bv, acc[s][t],0,0,0);
      }
    }
    #pragma unroll
    for (int s=0;s<2;s++)
      #pragma unroll
      for (int t=0;t<3;t++)
        #pragma unroll
        for (int r=0;r<4;r++)
          xd[(w*32 + s*16 + quad*4 + r)*52 + t*16 + mr] = acc[s][t][r];
  }
  __syncthreads();

  // ---- phase 2: LN per row (threads 0..127), write dt-cols to xln (bf16) + B/C to global ----
  if (tid < 128){
    f32x4* xr4 = (f32x4*)(xd + tid*52);
    f32x4 s = xr4[0];
    #pragma unroll
    for (int i=1;i<12;i++) s += xr4[i];
    float m = (s[0]+s[1]+s[2]+s[3]) * (1.f/48.f);
    f32x4 vs = {};
    #pragma unroll
    for (int i=0;i<12;i++){ f32x4 d = xr4[i] - m; vs += d*d; }
    float var = (vs[0]+vs[1]+vs[2]+vs[3]) * (1.f/48.f);
    float rstd = rsqrtf(var + 1e-5f);
    const f32x4* g4 = (const f32x4*)lnw;
    const f32x4* b4 = (const f32x4*)lnb;
    uint32_t* xlr = (uint32_t*)(xln + tid*40);
    #pragma unroll
    for (int i=0;i<8;i++){       // cols 0..31 -> xln bf16
      f32x4 v = (xr4[i] - m) * rstd * g4[i] + b4[i];
      xlr[2*i]   = (uint32_t)(uint16_t)f2bf(v[0]) | ((uint32_t)(uint16_t)f2bf(v[1]) << 16);
      xlr[2*i+1] = (uint32_t)(uint16_t)f2bf(v[2]) | ((uint32_t)(uint16_t)f2bf(v[3]) << 16);
    }
    f32x4* bco = (f32x4*)(bc + (size_t)(bm + tid)*16);
    #pragma unroll
    for (int i=8;i<12;i++)       // cols 32..47 -> bc f32
      bco[i-8] = (xr4[i] - m) * rstd * g4[i] + b4[i];
  }
  __syncthreads();

  // ---- phase 3: dt = xln[:,0:32] @ dtw^T (K=32, N=256) + bias + softplus -> dtln ----
  // softplus via hardware exp2/log2 path; for x>15 select x (err << bf16 ulp).
  {
    bf16x8 a[2];
    #pragma unroll
    for (int s=0;s<2;s++)
      a[s] = *(const bf16x8*)(xln + (w*32 + s*16 + mr)*40 + qk);
    #pragma unroll 4
    for (int nt=0; nt<16; nt++){
      int col = nt*16 + mr;
      bf16x8 bv = *(const bf16x8*)(dtw_bf + col*32 + qk);
      float dtbv = dtb[col];
      #pragma unroll
      for (int s=0;s<2;s++){
        f32x4 acc = {};
        acc = __builtin_amdgcn_mfma_f32_16x16x32_bf16(a[s], bv, acc,0,0,0);
        #pragma unroll
        for (int r=0;r<4;r++){
          int grow = bm + w*32 + s*16 + quad*4 + r;
          float dtv = acc[r] + dtbv;
          float e  = __expf(dtv);
          float sp = __logf(1.f + e);
          float delta = (dtv > 15.f) ? dtv : sp;
          dtln[(size_t)grow*256 + col] = f2bf(delta);
        }
      }
    }
  }
}

// ---------- k_scan: selective scan, one block per gb, u->y in place ----------
__global__ __launch_bounds__(256) void k_scan(short* __restrict__ ycat,
    const short* __restrict__ dtln, const float* __restrict__ bc,
    const float* __restrict__ Alog, const float* __restrict__ Dp)
{
  __shared__ __align__(16) float bcs[784];   // [49][16]
  int gb = blockIdx.x; int g = gb >> 9, b = gb & 511;
  int d = threadIdx.x;
  if (d < 196) ((f32x4*)bcs)[d] = ((const f32x4*)(bc + (size_t)gb*784))[d];
  __syncthreads();

  float A[8], h[8];
  {
    f32x4 a0 = *(const f32x4*)(Alog + d*8);
    f32x4 a1 = *(const f32x4*)(Alog + d*8 + 4);
    #pragma unroll
    for (int n=0;n<4;n++){ A[n] = -__expf(a0[n]); A[n+4] = -__expf(a1[n]); h[n]=0.f; h[n+4]=0.f; }
  }
  float Dpar = Dp[d];

  const short* dptr = dtln + (size_t)gb*49*256 + d;
  short* uptr = ycat + (size_t)(b*49)*2048 + g*512 + d;

  float dn = bf2f(dptr[0]);
  float un = bf2f(uptr[0]);
  for (int l=0;l<49;l++){
    float delta = dn, u = un;
    if (l < 48){ dn = bf2f(dptr[(l+1)*256]); un = bf2f(uptr[(l+1)*2048]); }
    const f32x4* bcr = (const f32x4*)(bcs + l*16);
    f32x4 B0 = bcr[0], B1 = bcr[1], C0 = bcr[2], C1 = bcr[3];
    float du = delta * u;
    float y = 0.f;
    #pragma unroll
    for (int n=0;n<4;n++){
      h[n] = h[n]*__expf(delta*A[n]) + du*B0[n];
      y += h[n]*C0[n];
    }
    #pragma unroll
    for (int n=0;n<4;n++){
      h[n+4] = h[n+4]*__expf(delta*A[n+4]) + du*B1[n];
      y += h[n+4]*C1[n];
    }
    uptr[l*2048] = f2bf(y + Dpar*u);
  }
}

// ---------- final GEMM: 256x128 tile, BK=32, K=2048 (NT=64), grid 392, XCD-swz ----------
__global__ __launch_bounds__(512) void k_gemmF(const short* __restrict__ ycat,
    const short* __restrict__ wogc, const float* __restrict__ biasc,
    float* __restrict__ out)
{
  __shared__ __align__(16) short S[24576];    // 48 KB: 2 buf x (A 16KB | B 8KB)
  int bid = blockIdx.x;                       // 392 = 8 * 49, bijective XCD swizzle
  int swz = (bid & 7) * 49 + (bid >> 3);
  int bm = (swz >> 2) * 256, bn = (swz & 3) * 128;
  int tid = threadIdx.x, lane = tid & 63, w = tid >> 6;

  int rl = lane >> 2;                                 // row within 16-row unit
  int gch = ((lane & 3) ^ ((lane >> 3) & 3)) * 8;     // pre-swizzled global chunk
  const short* aU0 = ycat + (size_t)(bm + w*32      + rl)*2048 + gch;
  const short* aU1 = ycat + (size_t)(bm + w*32 + 16 + rl)*2048 + gch;
  const short* bU  = wogc + (size_t)(bn + w*16      + rl)*2048 + gch;

  f32x4 acc[4][4] = {};
  kcore256x128<64>(aU0, aU1, bU, S, w, lane, acc);

  int wr = w >> 1, wc = w & 1, mr = lane & 15, quad = lane >> 4;
  #pragma unroll
  for (int mf = 0; mf < 4; ++mf)
    #pragma unroll
    for (int rr = 0; rr < 4; ++rr){
      int row = bm + wr*64 + mf*16 + quad*4 + rr;
      float* orow = out + (size_t)row*512;
      #pragma unroll
      for (int nf = 0; nf < 4; ++nf){
        int col = bn + wc*64 + nf*16 + mr;
        orow[col] = acc[mf][nf][rr] + biasc[col];
      }
    }
}

// ---------- launch ----------
extern "C" void kernel_launch(void* const* d_in, const int* in_sizes, int n_in,
                              void* d_out, int out_size, void* d_ws, size_t ws_size,
                              hipStream_t stream)
{
  const float* tokens    = (const float*)d_in[0];
  const float* pre_w[4]  = {(const float*)d_in[1], (const float*)d_in[3], (const float*)d_in[5], (const float*)d_in[7]};
  const float* pre_b[4]  = {(const float*)d_in[2], (const float*)d_in[4], (const float*)d_in[6], (const float*)d_in[8]};
  const float* post_w[4] = {(const float*)d_in[9], (const float*)d_in[11], (const float*)d_in[13], (const float*)d_in[15]};
  const float* post_b[4] = {(const float*)d_in[10], (const float*)d_in[12], (const float*)d_in[14], (const float*)d_in[16]};
  const float* in_proj   = (const float*)d_in[17];
  const float* conv_x_w  = (const float*)d_in[18];
  const float* conv_x_b  = (const float*)d_in[19];
  const float* conv_z_w  = (const float*)d_in[20];
  const float* conv_z_b  = (const float*)d_in[21];
  const float* x_proj_w  = (const float*)d_in[22];
  const float* ln_w      = (const float*)d_in[23];
  const float* ln_b      = (const float*)d_in[24];
  const float* dt_proj_w = (const float*)d_in[25];
  const float* dt_proj_b = (const float*)d_in[26];
  const float* A_log     = (const float*)d_in[27];
  const float* D_param   = (const float*)d_in[28];
  const float* out_proj  = (const float*)d_in[29];
  const float* gate_log  = (const float*)d_in[30];

  char* ws = (char*)d_ws;
  size_t o = 0;
  short* tok_bf   = (short*)(ws + o); o += 25690112;   // 12845056 bf16
  short* wpreT    = (short*)(ws + o); o += 2097152;    // 4x 512x512 bf16 (transposed)
  short* inp_bf   = (short*)(ws + o); o += 524288;
  short* postw_bf = (short*)(ws + o); o += 2097152;
  short* woutT    = (short*)(ws + o); o += 524288;
  short* wogc     = (short*)(ws + o); o += 2097152;    // 512 x 2048 bf16
  short* wxz      = (short*)(ws + o); o += 2097152;    // 4x 512x512 bf16
  short* xpw_bf   = (short*)(ws + o); o += 24576;      // 48x256 bf16
  short* dtw_bf   = (short*)(ws + o); o += 16384;      // 256x32 bf16
  float* bxz      = (float*)(ws + o); o += 8192;
  float* gains    = (float*)(ws + o); o += 64;
  float* biasc    = (float*)(ws + o); o += 2048;
  size_t scratch_off = o;
  o += 102760448;                                      // dtln + bc region
  short* ycat     = (short*)(ws + o); o += 102760448;  // 25088 x 2048 bf16
  short* dtln     = (short*)(ws + scratch_off);        // 51.4 MB
  float* bc       = (float*)(ws + scratch_off + 51380224);

  k_conv_all<<<1300, 256, 0, stream>>>(in_proj,
      post_w[0], post_w[1], post_w[2], post_w[3],
      x_proj_w, dt_proj_w, inp_bf, postw_bf, xpw_bf, dtw_bf);
  k_transp<<<dim3(64,5), 256, 0, stream>>>(pre_w[0], pre_w[1], pre_w[2], pre_w[3],
      out_proj, wpreT, woutT);
  k_tok<<<12544, 256, 0, stream>>>(tokens, tok_bf);
  k_bxz_gains<<<9, 256, 0, stream>>>(in_proj, pre_b[0], pre_b[1], pre_b[2], pre_b[3],
      gate_log, post_b[0], post_b[1], post_b[2], post_b[3], bxz, gains, biasc);
  k_wfuse<<<dim3(8,4,8), 256, 0, stream>>>(inp_bf, wpreT, postw_bf, woutT, gains, wxz, wogc);
  k_gemm1c<<<dim3(1648), 512, 0, stream>>>(tok_bf, wxz, bxz,
      conv_x_w, conv_x_b, conv_z_w, conv_z_b, ycat);
  k_xproj<<<784, 256, 0, stream>>>(ycat, xpw_bf, ln_w, ln_b, dtw_bf, dt_proj_b, dtln, bc);
  k_scan<<<2048, 256, 0, stream>>>(ycat, dtln, bc, A_log, D_param);
  k_gemmF<<<dim3(392), 512, 0, stream>>>(ycat, wogc, biasc, (float*)d_out);
}